// Round 8
// baseline (670.089 us; speedup 1.0000x reference)
//
#include <hip/hip_runtime.h>
#include <math.h>
#include <cstddef>

#define BB 4
#define LL 4096
#define DD 256
#define NST 8
#define RANK 16
#define HID 128
#define BL (BB*LL)          // 16384
#define BLD ((size_t)BL*DD) // 4194304
#define CH 256              // scan chunks
#define CLEN 16             // steps per chunk (CH*CLEN == LL)
#define XZS 512             // xz row stride (xin cols 0..255, z cols 256..511)

typedef __bf16 bf16x8 __attribute__((ext_vector_type(8)));
typedef float  f32x4  __attribute__((ext_vector_type(4)));

__device__ __forceinline__ float siluf(float x){ return x / (1.f + __expf(-x)); }
__device__ __forceinline__ float softplus_fast(float x){
  float r = __logf(1.f + __expf(x));
  return x > 15.f ? x : r;
}
// fp32 -> bf16 bits, round-to-nearest-even
__device__ __forceinline__ unsigned short f2bf(float x){
  union { float f; unsigned u; } v; v.f = x;
  unsigned r = v.u + 0x7fffu + ((v.u >> 16) & 1u);
  return (unsigned short)(r >> 16);
}
__device__ __forceinline__ float bf2f(unsigned short u){
  union { unsigned u32; float f; } c; c.u32 = ((unsigned)u) << 16;
  return c.f;
}

// --- async global->LDS, 16B/lane (1KB/wave-instr), linear LDS dest -------------
#define GLD16(gp, lp) __builtin_amdgcn_global_load_lds( \
    (const __attribute__((address_space(1))) unsigned int*)(gp), \
    (__attribute__((address_space(3))) unsigned int*)(lp), 16, 0, 0)

// swizzled-granule read: logical (row, g16) -> granule row*8 + (g16 ^ (row&7)).
#define LDSG(base, row, gq) \
  (*(const bf16x8*)((base) + ((((row) << 3) + ((gq) ^ ((row) & 7))) << 3)))

// --- manual grid barrier (sense-reversing, device scope) ------------------------
// Safe: grid == exactly 4 blocks/CU x 256 CUs, __launch_bounds__(256,4) caps VGPR
// at 128 so all 1024 blocks are co-resident (Guideline 16 pattern). Counters in
// workspace, zeroed by pre_kernel. Normal launch -> graph-capture safe.
__device__ __forceinline__ void grid_barrier(unsigned* cnt, unsigned* gen, unsigned nb){
  __syncthreads();
  if (threadIdx.x == 0){
    __threadfence();
    unsigned g = __hip_atomic_load(gen, __ATOMIC_RELAXED, __HIP_MEMORY_SCOPE_AGENT);
    unsigned a = __hip_atomic_fetch_add(cnt, 1u, __ATOMIC_ACQ_REL, __HIP_MEMORY_SCOPE_AGENT);
    if (a == nb - 1u){
      __hip_atomic_store(cnt, 0u, __ATOMIC_RELAXED, __HIP_MEMORY_SCOPE_AGENT);
      __hip_atomic_fetch_add(gen, 1u, __ATOMIC_RELEASE, __HIP_MEMORY_SCOPE_AGENT);
    } else {
      while (__hip_atomic_load(gen, __ATOMIC_ACQUIRE, __HIP_MEMORY_SCOPE_AGENT) == g)
        __builtin_amdgcn_s_sleep(8);
    }
    __threadfence();
  }
  __syncthreads();
}

// =============== Pre: RMSNorm (both streams) + weight cvt + barrier init =========
__global__ __launch_bounds__(256) void pre_kernel(
    const float* __restrict__ x0, const float* __restrict__ w0, unsigned short* __restrict__ o0b,
    const float* __restrict__ x1, const float* __restrict__ w1, unsigned short* __restrict__ o1b,
    const float* __restrict__ sA,
    const float* __restrict__ s0, const float* __restrict__ s1,
    const float* __restrict__ s2, const float* __restrict__ s3,
    const float* __restrict__ s4,
    unsigned short* __restrict__ d1, unsigned short* __restrict__ d2,
    unsigned* __restrict__ bar)
{
  int blk = blockIdx.x;
  if (blk == 8192 && threadIdx.x < 2) bar[threadIdx.x] = 0;
  if (blk < 8192){
    const float* x; const float* w; unsigned short* o; size_t tok;
    int wv = threadIdx.x >> 6, lane = threadIdx.x & 63;
    if (blk < 4096){ x = x0; w = w0; o = o0b; tok = (size_t)blk*4 + wv; }
    else           { x = x1; w = w1; o = o1b; tok = (size_t)(blk-4096)*4 + wv; }
    float4 v = ((const float4*)(x + tok*DD))[lane];
    float s = v.x*v.x + v.y*v.y + v.z*v.z + v.w*v.w;
    #pragma unroll
    for (int m = 1; m < 64; m <<= 1) s += __shfl_xor(s, m, 64);
    float scale = 1.f / (sqrtf(s) * (1.f/16.f) + 1e-6f);
    float4 wvv = ((const float4*)w)[lane];
    ushort4 r;
    r.x = f2bf(v.x*scale*wvv.x); r.y = f2bf(v.y*scale*wvv.y);
    r.z = f2bf(v.z*scale*wvv.z); r.w = f2bf(v.w*scale*wvv.w);
    ((ushort4*)(o + tok*DD))[lane] = r;
    return;
  }
  int i = (blk - 8192)*256 + threadIdx.x;   // 0..278527
  if (i >= 278528) return;
  if (i < 131072){ d1[i] = f2bf(sA[i]); return; }
  int j = i - 131072;
  float v;
  if (j < 8192)        v = s0[j];
  else if (j < 16384)  v = s1[j - 8192];
  else if (j < 81920)  v = s2[j - 16384];
  else if (j < 114688) v = s3[j - 81920];
  else                 v = s4[j - 114688];
  d2[j] = f2bf(v);
}

// ---------------- bf16 MFMA GEMM, 64x64 tile, BK=64, global_load_lds staging -----
// EPI: 0 = C=acc ; 2 = C=acc+Add ; 3 = Cb=bf16(acc)
template<int EPI>
__global__ __launch_bounds__(256) void gemm_mfma(
    const unsigned short* __restrict__ A, const unsigned short* __restrict__ Bw,
    float* __restrict__ C, const float* __restrict__ Add,
    unsigned short* __restrict__ Cb, int M, int ldc, int K)
{
  constexpr int BK = 64;
  __shared__ __align__(16) unsigned short AsL[64*64];
  __shared__ __align__(16) unsigned short BsL[64*64];
  int tid  = threadIdx.x;
  int row0 = blockIdx.x * 64;
  int col0 = blockIdx.y * 64;
  int wave = tid >> 6, lane = tid & 63;
  int wm = (wave >> 1) * 32, wn = (wave & 1) * 32;
  int lm = lane & 15, kq = lane >> 4;

  int q0 = wave*128 + lane, q1 = q0 + 64;
  int ra = q0 >> 3, ga = (q0 & 7) ^ (ra & 7);
  int rb = q1 >> 3, gb = (q1 & 7) ^ (rb & 7);
  const unsigned short* A0 = A  + (size_t)(row0 + ra)*K + ga*8;
  const unsigned short* A1 = A  + (size_t)(row0 + rb)*K + gb*8;
  const unsigned short* B0 = Bw + (size_t)(col0 + ra)*K + ga*8;
  const unsigned short* B1 = Bw + (size_t)(col0 + rb)*K + gb*8;
  unsigned short* lA0 = AsL + wave*1024;
  unsigned short* lB0 = BsL + wave*1024;

  f32x4 acc[2][2];
  #pragma unroll
  for (int i = 0; i < 2; i++)
    #pragma unroll
    for (int j = 0; j < 2; j++) acc[i][j] = (f32x4){0.f,0.f,0.f,0.f};

  for (int k0 = 0; k0 < K; k0 += BK){
    GLD16(A0 + k0, lA0);       GLD16(A1 + k0, lA0 + 512);
    GLD16(B0 + k0, lB0);       GLD16(B1 + k0, lB0 + 512);
    __syncthreads();
    #pragma unroll
    for (int ks = 0; ks < 2; ks++){
      bf16x8 af[2], bfv[2];
      #pragma unroll
      for (int i = 0; i < 2; i++) af[i]  = LDSG(AsL, wm + i*16 + lm, ks*4 + kq);
      #pragma unroll
      for (int j = 0; j < 2; j++) bfv[j] = LDSG(BsL, wn + j*16 + lm, ks*4 + kq);
      #pragma unroll
      for (int i = 0; i < 2; i++)
        #pragma unroll
        for (int j = 0; j < 2; j++)
          acc[i][j] = __builtin_amdgcn_mfma_f32_16x16x32_bf16(af[i], bfv[j], acc[i][j], 0, 0, 0);
    }
    __syncthreads();
  }

  #pragma unroll
  for (int i = 0; i < 2; i++){
    int rbase = row0 + wm + i*16 + kq*4;
    #pragma unroll
    for (int j = 0; j < 2; j++){
      int col = col0 + wn + j*16 + lm;
      #pragma unroll
      for (int r = 0; r < 4; r++){
        size_t idx = (size_t)(rbase + r)*ldc + col;
        float v = acc[i][j][r];
        if constexpr (EPI == 2) v += Add[idx];
        if constexpr (EPI != 3) C[idx] = v;
        if constexpr (EPI == 3) Cb[idx] = f2bf(v);
      }
    }
  }
}

// =============== Merged xz + xproj GEMM (gload_lds staging) ======================
__global__ __launch_bounds__(256) void gemm_xzxp(
    const unsigned short* __restrict__ A0i, const unsigned short* __restrict__ A1i,
    const unsigned short* __restrict__ B0i, const unsigned short* __restrict__ B1i,
    unsigned short* __restrict__ Cxz, float* __restrict__ Cxd)
{
  constexpr int BK = 64, K = 256;
  __shared__ __align__(16) unsigned short AsL[64*64];
  __shared__ __align__(16) unsigned short BsL[64*64];
  int tid  = threadIdx.x;
  bool xp  = (blockIdx.y == 8);
  const unsigned short* A  = xp ? A1i : A0i;
  const unsigned short* Bw = xp ? B1i : B0i;
  int row0 = blockIdx.x * 64;
  int col0 = xp ? 0 : blockIdx.y * 64;
  int wave = tid >> 6, lane = tid & 63;
  int wm = (wave >> 1) * 32, wn = (wave & 1) * 32;
  int lm = lane & 15, kq = lane >> 4;

  int q0 = wave*128 + lane, q1 = q0 + 64;
  int ra = q0 >> 3, ga = (q0 & 7) ^ (ra & 7);
  int rb = q1 >> 3, gb = (q1 & 7) ^ (rb & 7);
  const unsigned short* A0 = A  + (size_t)(row0 + ra)*K + ga*8;
  const unsigned short* A1 = A  + (size_t)(row0 + rb)*K + gb*8;
  const unsigned short* B0 = Bw + (size_t)(col0 + ra)*K + ga*8;
  const unsigned short* B1 = Bw + (size_t)(col0 + rb)*K + gb*8;
  unsigned short* lA0 = AsL + wave*1024;
  unsigned short* lB0 = BsL + wave*1024;

  f32x4 acc[2][2];
  #pragma unroll
  for (int i = 0; i < 2; i++)
    #pragma unroll
    for (int j = 0; j < 2; j++) acc[i][j] = (f32x4){0.f,0.f,0.f,0.f};

  for (int k0 = 0; k0 < K; k0 += BK){
    GLD16(A0 + k0, lA0);       GLD16(A1 + k0, lA0 + 512);
    GLD16(B0 + k0, lB0);       GLD16(B1 + k0, lB0 + 512);
    __syncthreads();
    #pragma unroll
    for (int ks = 0; ks < 2; ks++){
      bf16x8 af[2], bfv[2];
      #pragma unroll
      for (int i = 0; i < 2; i++) af[i]  = LDSG(AsL, wm + i*16 + lm, ks*4 + kq);
      #pragma unroll
      for (int j = 0; j < 2; j++) bfv[j] = LDSG(BsL, wn + j*16 + lm, ks*4 + kq);
      #pragma unroll
      for (int i = 0; i < 2; i++)
        #pragma unroll
        for (int j = 0; j < 2; j++)
          acc[i][j] = __builtin_amdgcn_mfma_f32_16x16x32_bf16(af[i], bfv[j], acc[i][j], 0, 0, 0);
    }
    __syncthreads();
  }

  #pragma unroll
  for (int i = 0; i < 2; i++){
    int rbase = row0 + wm + i*16 + kq*4;
    #pragma unroll
    for (int j = 0; j < 2; j++){
      int col = col0 + wn + j*16 + lm;
      #pragma unroll
      for (int r = 0; r < 4; r++){
        float v = acc[i][j][r];
        if (xp) Cxd[(size_t)(rbase + r)*64  + col] = v;
        else    Cxz[(size_t)(rbase + r)*XZS + col] = f2bf(v);
      }
    }
  }
}

// =============== fc1: fp32-A GEMM (A padded-LDS convert; B gload_lds) ============
__global__ __launch_bounds__(256) void gemm_fc1(
    const float* __restrict__ A, const unsigned short* __restrict__ Bw,
    float* __restrict__ C)
{
  constexpr int BK = 64, PAD = 8, K = 256, LDC = 128;
  __shared__ __align__(16) unsigned short As[64][BK+PAD];
  __shared__ __align__(16) unsigned short BsL[64*64];
  int tid  = threadIdx.x;
  int row0 = blockIdx.x * 64;
  int col0 = blockIdx.y * 64;
  int wave = tid >> 6, lane = tid & 63;
  int wm = (wave >> 1) * 32, wn = (wave & 1) * 32;
  int lm = lane & 15, kq = lane >> 4;
  int sr = tid >> 2, sc16 = (tid & 3) * 16;

  int q0 = wave*128 + lane, q1 = q0 + 64;
  int ra = q0 >> 3, ga = (q0 & 7) ^ (ra & 7);
  int rb = q1 >> 3, gb = (q1 & 7) ^ (rb & 7);
  const unsigned short* B0 = Bw + (size_t)(col0 + ra)*K + ga*8;
  const unsigned short* B1 = Bw + (size_t)(col0 + rb)*K + gb*8;
  unsigned short* lB0 = BsL + wave*1024;

  f32x4 acc[2][2];
  #pragma unroll
  for (int i = 0; i < 2; i++)
    #pragma unroll
    for (int j = 0; j < 2; j++) acc[i][j] = (f32x4){0.f,0.f,0.f,0.f};

  for (int k0 = 0; k0 < K; k0 += BK){
    GLD16(B0 + k0, lB0);       GLD16(B1 + k0, lB0 + 512);
    const float* ap = &A[(size_t)(row0 + sr)*K + k0 + sc16];
    #pragma unroll
    for (int q = 0; q < 4; q++){
      float4 f = *(const float4*)(ap + q*4);
      ushort4 u; u.x = f2bf(f.x); u.y = f2bf(f.y); u.z = f2bf(f.z); u.w = f2bf(f.w);
      *(ushort4*)&As[sr][sc16 + q*4] = u;
    }
    __syncthreads();
    #pragma unroll
    for (int ks = 0; ks < 2; ks++){
      bf16x8 af[2], bfv[2];
      #pragma unroll
      for (int i = 0; i < 2; i++) af[i]  = *(const bf16x8*)&As[wm + i*16 + lm][ks*32 + kq*8];
      #pragma unroll
      for (int j = 0; j < 2; j++) bfv[j] = LDSG(BsL, wn + j*16 + lm, ks*4 + kq);
      #pragma unroll
      for (int i = 0; i < 2; i++)
        #pragma unroll
        for (int j = 0; j < 2; j++)
          acc[i][j] = __builtin_amdgcn_mfma_f32_16x16x32_bf16(af[i], bfv[j], acc[i][j], 0, 0, 0);
    }
    __syncthreads();
  }

  #pragma unroll
  for (int i = 0; i < 2; i++){
    int rbase = row0 + wm + i*16 + kq*4;
    #pragma unroll
    for (int j = 0; j < 2; j++){
      int col = col0 + wn + j*16 + lm;
      #pragma unroll
      for (int r = 0; r < 4; r++)
        C[(size_t)(rbase + r)*LDC + col] = acc[i][j][r];
    }
  }
}

// =============== fc2 with dwconv+silu fused into A-staging (B gload_lds) =========
__global__ __launch_bounds__(256) void gemm_fc2dw(
    const float* __restrict__ m1, const unsigned short* __restrict__ Bw,
    const float* __restrict__ dww, const float* __restrict__ dwb,
    float* __restrict__ C)
{
  constexpr int BK = 64, PAD = 8, K = 128, LDC = 256;
  __shared__ __align__(16) unsigned short As[64][BK+PAD];
  __shared__ __align__(16) unsigned short BsL[64*64];
  __shared__ float wS[HID*3];
  __shared__ float bS[HID];
  int tid  = threadIdx.x;
  if (tid < HID){
    bS[tid] = dwb[tid];
    wS[tid*3+0] = dww[tid*3+0];
    wS[tid*3+1] = dww[tid*3+1];
    wS[tid*3+2] = dww[tid*3+2];
  }
  __syncthreads();

  int row0 = blockIdx.x * 64;
  int col0 = blockIdx.y * 64;
  int wave = tid >> 6, lane = tid & 63;
  int wm = (wave >> 1) * 32, wn = (wave & 1) * 32;
  int lm = lane & 15, kq = lane >> 4;
  int r16 = tid >> 4, cc = (tid & 15) * 4;

  int q0 = wave*128 + lane, q1 = q0 + 64;
  int ra = q0 >> 3, ga = (q0 & 7) ^ (ra & 7);
  int rb = q1 >> 3, gb = (q1 & 7) ^ (rb & 7);
  const unsigned short* B0 = Bw + (size_t)(col0 + ra)*K + ga*8;
  const unsigned short* B1 = Bw + (size_t)(col0 + rb)*K + gb*8;
  unsigned short* lB0 = BsL + wave*1024;

  f32x4 acc[2][2];
  #pragma unroll
  for (int i = 0; i < 2; i++)
    #pragma unroll
    for (int j = 0; j < 2; j++) acc[i][j] = (f32x4){0.f,0.f,0.f,0.f};

  for (int k0 = 0; k0 < K; k0 += BK){
    GLD16(B0 + k0, lB0);       GLD16(B1 + k0, lB0 + 512);
    #pragma unroll
    for (int pp = 0; pp < 4; pp++){
      int r = pp*16 + r16;
      int t = row0 + r;
      int tl = t & (LL-1);
      int c = k0 + cc;
      const float* mrow = &m1[(size_t)t*HID + c];
      float4 vm = *(const float4*)mrow;
      float4 vp = (tl > 0)      ? *(const float4*)(mrow - HID) : (float4){0,0,0,0};
      float4 vn = (tl < LL-1)   ? *(const float4*)(mrow + HID) : (float4){0,0,0,0};
      float a0 = bS[c+0] + wS[(c+0)*3]*vp.x + wS[(c+0)*3+1]*vm.x + wS[(c+0)*3+2]*vn.x;
      float a1 = bS[c+1] + wS[(c+1)*3]*vp.y + wS[(c+1)*3+1]*vm.y + wS[(c+1)*3+2]*vn.y;
      float a2 = bS[c+2] + wS[(c+2)*3]*vp.z + wS[(c+2)*3+1]*vm.z + wS[(c+2)*3+2]*vn.z;
      float a3 = bS[c+3] + wS[(c+3)*3]*vp.w + wS[(c+3)*3+1]*vm.w + wS[(c+3)*3+2]*vn.w;
      ushort4 u;
      u.x = f2bf(siluf(a0)); u.y = f2bf(siluf(a1));
      u.z = f2bf(siluf(a2)); u.w = f2bf(siluf(a3));
      *(ushort4*)&As[r][cc] = u;
    }
    __syncthreads();
    #pragma unroll
    for (int ks = 0; ks < 2; ks++){
      bf16x8 af[2], bfv[2];
      #pragma unroll
      for (int i = 0; i < 2; i++) af[i]  = *(const bf16x8*)&As[wm + i*16 + lm][ks*32 + kq*8];
      #pragma unroll
      for (int j = 0; j < 2; j++) bfv[j] = LDSG(BsL, wn + j*16 + lm, ks*4 + kq);
      #pragma unroll
      for (int i = 0; i < 2; i++)
        #pragma unroll
        for (int j = 0; j < 2; j++)
          acc[i][j] = __builtin_amdgcn_mfma_f32_16x16x32_bf16(af[i], bfv[j], acc[i][j], 0, 0, 0);
    }
    __syncthreads();
  }

  #pragma unroll
  for (int i = 0; i < 2; i++){
    int rbase = row0 + wm + i*16 + kq*4;
    #pragma unroll
    for (int j = 0; j < 2; j++){
      int col = col0 + wn + j*16 + lm;
      #pragma unroll
      for (int r = 0; r < 4; r++){
        size_t idx = (size_t)(rbase + r)*LDC + col;
        C[idx] = C[idx] + acc[i][j][r];
      }
    }
  }
}

// =================== FUSED persistent scan: front + carry + back =================
// Grid = CH*BB = 1024 blocks (exactly 4/CU at launch_bounds(256,4)). Block (c,b)
// runs front for fwd chunk c AND bwd chunk CH-1-c (same token range), keeping the
// (y0,de) packs in REGISTERS and C-tiles in LDS across two manual grid barriers;
// the carry scan (old scan_p2) runs on waves 0-1. Kills the 67 MB xde roundtrip.
// Front/scan/back bodies are the measured-best versions, numerics identical.
__global__ __launch_bounds__(256, 4) void fused_scan(
    const unsigned short* __restrict__ xz,
    const float* __restrict__ xd,
    const float* __restrict__ cwf, const float* __restrict__ cbf,
    const float* __restrict__ cwb, const float* __restrict__ cbb,
    const float* __restrict__ dtwf, const float* __restrict__ dtbf,
    const float* __restrict__ dtwb, const float* __restrict__ dtbb,
    const float* __restrict__ Alogf, const float* __restrict__ Alogb,
    const float* __restrict__ Dfp, const float* __restrict__ Dbp,
    const float* __restrict__ wn,
    unsigned short* __restrict__ outb,
    float* __restrict__ Sp, float* H, unsigned* bar)
{
  int blk = blockIdx.x;
  int c   = blk >> 2;          // 0..255
  int b   = blk & 3;
  int d   = threadIdx.x;
  int cbk = CH-1-c;

  __shared__ float sdt[CLEN][16];
  __shared__ float sB [CLEN][8];
  __shared__ float sCf[CLEN][8];
  __shared__ float sCb[CLEN][8];
  __shared__ float red[CLEN][4];
  __shared__ float sscale[CLEN];

  unsigned pkF[CLEN], pkB[CLEN];

  // ---------------- front for one direction (lambda, run twice) ----------------
  auto run_front = [&](int chunk, int dirv, float (&sCx)[CLEN][8], unsigned* pk){
    int s0 = chunk*CLEN;
    __syncthreads();   // protect prior LDS readers before restage
    #pragma unroll
    for (int e = d; e < CLEN*32; e += 256){
      int lt = e >> 5, col = e & 31;
      int pos = s0 + lt;
      int row = dirv ? (LL-1-pos) : pos;
      float v = xd[((size_t)b*LL + row)*64 + dirv*32 + col];
      if (col < 16)      sdt[lt][col]    = v;
      else if (col < 24) sB [lt][col-16] = v;
      else               sCx[lt][col-24] = v;
    }
    __syncthreads();

    float4 cw = ((const float4*)(dirv ? cwb : cwf))[d];
    float cb  = (dirv ? cbb : cbf)[d];
    const float* dtw = (dirv ? dtwb : dtwf) + d*RANK;
    float4 w0 = ((const float4*)dtw)[0], w1 = ((const float4*)dtw)[1];
    float4 w2 = ((const float4*)dtw)[2], w3 = ((const float4*)dtw)[3];
    float dtb = (dirv ? dtbb : dtbf)[d];
    float Dd  = (dirv ? Dbp : Dfp)[d];

    const unsigned short* xp = xz + (size_t)b*LL*XZS + d;
    #define LDX(pos) ((pos) >= 0 ? bf2f(xp[(size_t)(dirv ? (LL-1-(pos)) : (pos))*XZS]) : 0.f)
    float xv[CLEN+3];
    xv[0] = LDX(s0-3); xv[1] = LDX(s0-2); xv[2] = LDX(s0-1);
    #pragma unroll
    for (int i = 0; i < CLEN; i++) xv[3+i] = LDX(s0+i);
    #undef LDX

    #pragma unroll
    for (int i = 0; i < CLEN; i++){
      float xc = cb;
      xc = fmaf(cw.x, xv[i],   xc); xc = fmaf(cw.y, xv[i+1], xc);
      xc = fmaf(cw.z, xv[i+2], xc); xc = fmaf(cw.w, xv[i+3], xc);
      xc = siluf(xc);
      const float* dt = &sdt[i][0];
      float de = dtb;
      de = fmaf(dt[0],w0.x, fmaf(dt[1],w0.y, fmaf(dt[2],w0.z, fmaf(dt[3],w0.w, de))));
      de = fmaf(dt[4],w1.x, fmaf(dt[5],w1.y, fmaf(dt[6],w1.z, fmaf(dt[7],w1.w, de))));
      de = fmaf(dt[8],w2.x, fmaf(dt[9],w2.y, fmaf(dt[10],w2.z, fmaf(dt[11],w2.w, de))));
      de = fmaf(dt[12],w3.x, fmaf(dt[13],w3.y, fmaf(dt[14],w3.z, fmaf(dt[15],w3.w, de))));
      de = softplus_fast(de);
      pk[i] = (unsigned)f2bf(xc) | ((unsigned)f2bf(de) << 16);
    }

    const float* Alog = dirv ? Alogb : Alogf;
    float A[NST];
    bool fast = true;
    #pragma unroll
    for (int n = 0; n < NST; n++){
      A[n] = -__expf(Alog[d*NST + n]);
      fast = fast && (fabsf(A[n] + (float)(n+1)) < 1e-3f);
    }
    float h[NST];
    #pragma unroll
    for (int n = 0; n < NST; n++) h[n] = 0.f;
    float S = 0.f;

    if (fast){
      #pragma unroll
      for (int t = 0; t < CLEN; t++){
        unsigned pkv = pk[t];
        float xc = bf2f((unsigned short)(pkv & 0xffffu));
        float de = bf2f((unsigned short)(pkv >> 16));
        S += de;
        float dux = de * xc;
        const float* Bv = &sB[t][0];
        const float* Cv = &sCx[t][0];
        float e1 = __expf(-de);
        float dA = e1;
        float acc = xc * Dd;
        h[0] = fmaf(dA, h[0], dux*Bv[0]); acc = fmaf(h[0], Cv[0], acc); dA *= e1;
        h[1] = fmaf(dA, h[1], dux*Bv[1]); acc = fmaf(h[1], Cv[1], acc); dA *= e1;
        h[2] = fmaf(dA, h[2], dux*Bv[2]); acc = fmaf(h[2], Cv[2], acc); dA *= e1;
        h[3] = fmaf(dA, h[3], dux*Bv[3]); acc = fmaf(h[3], Cv[3], acc); dA *= e1;
        h[4] = fmaf(dA, h[4], dux*Bv[4]); acc = fmaf(h[4], Cv[4], acc); dA *= e1;
        h[5] = fmaf(dA, h[5], dux*Bv[5]); acc = fmaf(h[5], Cv[5], acc); dA *= e1;
        h[6] = fmaf(dA, h[6], dux*Bv[6]); acc = fmaf(h[6], Cv[6], acc); dA *= e1;
        h[7] = fmaf(dA, h[7], dux*Bv[7]); acc = fmaf(h[7], Cv[7], acc);
        pk[t] = (pkv & 0xffff0000u) | (unsigned)f2bf(acc);
      }
    } else {
      #pragma unroll
      for (int t = 0; t < CLEN; t++){
        unsigned pkv = pk[t];
        float xc = bf2f((unsigned short)(pkv & 0xffffu));
        float de = bf2f((unsigned short)(pkv >> 16));
        S += de;
        float dux = de * xc;
        const float* Bv = &sB[t][0];
        const float* Cv = &sCx[t][0];
        float acc = xc * Dd;
        #pragma unroll
        for (int n = 0; n < NST; n++){
          h[n] = fmaf(__expf(de*A[n]), h[n], dux*Bv[n]);
          acc = fmaf(h[n], Cv[n], acc);
        }
        pk[t] = (pkv & 0xffff0000u) | (unsigned)f2bf(acc);
      }
    }

    size_t ob = ((((size_t)dirv*CH + chunk)*BB + b)*DD + d)*NST;
    float4 h0v, h1v;
    h0v.x=h[0]; h0v.y=h[1]; h0v.z=h[2]; h0v.w=h[3];
    h1v.x=h[4]; h1v.y=h[5]; h1v.z=h[6]; h1v.w=h[7];
    *(float4*)&H[ob]   = h0v; *(float4*)&H[ob+4] = h1v;
    Sp[((size_t)(dirv*CH + chunk)*BB + b)*DD + d] = S;
  };

  run_front(c,   0, sCf, pkF);
  run_front(cbk, 1, sCb, pkB);

  grid_barrier(bar, bar+1, CH*BB);

  // ---------------- carry scan (old scan_p2): waves 0-1, one unit each ----------
  {
    int wave = d >> 6, lane = d & 63;
    if (wave < 2){
      const int SEGC = CH/8;
      int u   = blk*2 + wave;        // 0..2047
      int d2  = u & (DD-1);
      int b2  = (u >> 8) & (BB-1);
      int dir2= u >> 10;
      int seg = lane >> 3, n = lane & 7;
      float A = -__expf((dir2 ? Alogb : Alogf)[d2*NST + n]);
      const size_t sstr = (size_t)BB*DD;
      const size_t hstr = (size_t)BB*DD*NST;
      size_t sb = (size_t)dir2*CH*sstr + (size_t)b2*DD + d2;
      size_t hb = (size_t)dir2*CH*hstr + ((size_t)b2*DD + d2)*NST + n;
      int c0 = seg*SEGC;

      float hv[SEGC];
      float h = 0.f, Ss = 0.f;
      #pragma unroll
      for (int k = 0; k < SEGC; k++){
        float s = Sp[sb + (size_t)(c0+k)*sstr];
        hv[k]  = H [hb + (size_t)(c0+k)*hstr];
        Ss += s;
        h = fmaf(__expf(s*A), h, hv[k]);
      }
      float pi = __expf(Ss*A), hi = h;
      #pragma unroll
      for (int off = 8; off < 64; off <<= 1){
        float hprev = __shfl_up(hi, off, 64);
        float pprev = __shfl_up(pi, off, 64);
        if (lane >= off){ hi = fmaf(pi, hprev, hi); pi *= pprev; }
      }
      float hin = __shfl_up(hi, 8, 64);
      h = (seg == 0) ? 0.f : hin;
      #pragma unroll
      for (int k = 0; k < SEGC; k++){
        float s = Sp[sb + (size_t)(c0+k)*sstr];
        size_t hix = hb + (size_t)(c0+k)*hstr;
        H[hix] = h;
        h = fmaf(__expf(s*A), h, hv[k]);
      }
    }
  }

  grid_barrier(bar, bar+1, CH*BB);

  // ---------------- back: correction + combine + rmsnorm + gate -----------------
  int T0 = c*CLEN;
  float Af[NST], Ab[NST];
  bool fast = true;
  #pragma unroll
  for (int n = 0; n < NST; n++){
    Af[n] = -__expf(Alogf[d*NST + n]);
    Ab[n] = -__expf(Alogb[d*NST + n]);
    fast = fast && (fabsf(Af[n] + (float)(n+1)) < 1e-3f)
                && (fabsf(Ab[n] + (float)(n+1)) < 1e-3f);
  }

  float vf[CLEN];

  // ---- forward correction (pack retained in pkF, C in sCf) ----
  {
    float hn[NST];
    size_t ib = (((size_t)c*BB + b)*DD + d)*NST;                 // dir=0
    float4 a0 = *(const float4*)&H[ib];
    float4 a1 = *(const float4*)&H[ib+4];
    hn[0]=a0.x; hn[1]=a0.y; hn[2]=a0.z; hn[3]=a0.w;
    hn[4]=a1.x; hn[5]=a1.y; hn[6]=a1.z; hn[7]=a1.w;
    float S = 0.f;
    if (fast){
      #pragma unroll
      for (int t = 0; t < CLEN; t++){
        float y0 = bf2f((unsigned short)(pkF[t] & 0xffffu));
        float de = bf2f((unsigned short)(pkF[t] >> 16));
        S += de;
        float E = __expf(-S);
        float q = E;
        float corr = q * (hn[0]*sCf[t][0]);
        q *= E; corr = fmaf(q, hn[1]*sCf[t][1], corr);
        q *= E; corr = fmaf(q, hn[2]*sCf[t][2], corr);
        q *= E; corr = fmaf(q, hn[3]*sCf[t][3], corr);
        q *= E; corr = fmaf(q, hn[4]*sCf[t][4], corr);
        q *= E; corr = fmaf(q, hn[5]*sCf[t][5], corr);
        q *= E; corr = fmaf(q, hn[6]*sCf[t][6], corr);
        q *= E; corr = fmaf(q, hn[7]*sCf[t][7], corr);
        vf[t] = y0 + corr;
      }
    } else {
      #pragma unroll
      for (int t = 0; t < CLEN; t++){
        float y0 = bf2f((unsigned short)(pkF[t] & 0xffffu));
        float de = bf2f((unsigned short)(pkF[t] >> 16));
        S += de;
        float corr = 0.f;
        #pragma unroll
        for (int n = 0; n < NST; n++)
          corr = fmaf(__expf(S*Af[n]), hn[n]*sCf[t][n], corr);
        vf[t] = y0 + corr;
      }
    }
  }

  // ---- backward correction (pkB, sCb); token j pairs with bwd k=15-j ----
  {
    float hn[NST];
    size_t ib = ((((size_t)CH + cbk)*BB + b)*DD + d)*NST;        // dir=1
    float4 a0 = *(const float4*)&H[ib];
    float4 a1 = *(const float4*)&H[ib+4];
    hn[0]=a0.x; hn[1]=a0.y; hn[2]=a0.z; hn[3]=a0.w;
    hn[4]=a1.x; hn[5]=a1.y; hn[6]=a1.z; hn[7]=a1.w;
    float S = 0.f;
    if (fast){
      #pragma unroll
      for (int t = 0; t < CLEN; t++){
        float y0 = bf2f((unsigned short)(pkB[t] & 0xffffu));
        float de = bf2f((unsigned short)(pkB[t] >> 16));
        S += de;
        float E = __expf(-S);
        float q = E;
        float corr = q * (hn[0]*sCb[t][0]);
        q *= E; corr = fmaf(q, hn[1]*sCb[t][1], corr);
        q *= E; corr = fmaf(q, hn[2]*sCb[t][2], corr);
        q *= E; corr = fmaf(q, hn[3]*sCb[t][3], corr);
        q *= E; corr = fmaf(q, hn[4]*sCb[t][4], corr);
        q *= E; corr = fmaf(q, hn[5]*sCb[t][5], corr);
        q *= E; corr = fmaf(q, hn[6]*sCb[t][6], corr);
        q *= E; corr = fmaf(q, hn[7]*sCb[t][7], corr);
        int j = 15 - t;
        vf[j] = 0.5f*(vf[j] + y0 + corr);
      }
    } else {
      #pragma unroll
      for (int t = 0; t < CLEN; t++){
        float y0 = bf2f((unsigned short)(pkB[t] & 0xffffu));
        float de = bf2f((unsigned short)(pkB[t] >> 16));
        S += de;
        float corr = 0.f;
        #pragma unroll
        for (int n = 0; n < NST; n++)
          corr = fmaf(__expf(S*Ab[n]), hn[n]*sCb[t][n], corr);
        int j = 15 - t;
        vf[j] = 0.5f*(vf[j] + y0 + corr);
      }
    }
  }

  // ---- per-token RMS reduce over d ----
  int wave = d >> 6, lane = d & 63;
  #pragma unroll
  for (int j = 0; j < CLEN; j++){
    float s = vf[j]*vf[j];
    #pragma unroll
    for (int m = 1; m < 64; m <<= 1) s += __shfl_xor(s, m, 64);
    if (lane == 0) red[j][wave] = s;
  }
  __syncthreads();
  if (d < CLEN){
    float s = red[d][0] + red[d][1] + red[d][2] + red[d][3];
    sscale[d] = 1.f / (sqrtf(s)*(1.f/16.f) + 1e-6f);
  }
  __syncthreads();

  float wd = wn[d];
  #pragma unroll
  for (int j = 0; j < CLEN; j++){
    size_t tok = (size_t)b*LL + T0 + j;
    float z = bf2f(xz[tok*XZS + 256 + d]);
    outb[tok*DD + d] = f2bf(vf[j]*sscale[j]*wd*siluf(z));
  }
}

extern "C" void kernel_launch(void* const* d_in, const int* in_sizes, int n_in,
                              void* d_out, int out_size, void* d_ws, size_t ws_size,
                              hipStream_t stream)
{
  const float* x0        = (const float*)d_in[0];
  const float* x1        = (const float*)d_in[1];
  const float* w_norm0   = (const float*)d_in[2];
  const float* w_norm1   = (const float*)d_in[3];
  const float* in_proj_w = (const float*)d_in[4];
  const float* conv_w_f  = (const float*)d_in[5];
  const float* conv_b_f  = (const float*)d_in[6];
  const float* xproj_w_f = (const float*)d_in[7];
  const float* dtproj_w_f= (const float*)d_in[8];
  const float* dtproj_b_f= (const float*)d_in[9];
  const float* A_log_f   = (const float*)d_in[10];
  const float* D_f       = (const float*)d_in[11];
  const float* conv_w_bw = (const float*)d_in[12];
  const float* conv_b_bw = (const float*)d_in[13];
  const float* xproj_w_bw= (const float*)d_in[14];
  const float* dtproj_w_bw=(const float*)d_in[15];
  const float* dtproj_b_bw=(const float*)d_in[16];
  const float* A_log_bw  = (const float*)d_in[17];
  const float* D_bw      = (const float*)d_in[18];
  const float* norm_y_w  = (const float*)d_in[19];
  const float* out_proj_w= (const float*)d_in[20];
  const float* fc1_w     = (const float*)d_in[21];
  const float* dw_w      = (const float*)d_in[22];
  const float* dw_b      = (const float*)d_in[23];
  const float* fc2_w     = (const float*)d_in[24];
  float* out = (float*)d_out;
  float* ws  = (float*)d_ws;

  // region map (floats, BLD each), lifetime-reused
  float* r0 = ws + 0*BLD;   // h0b (bf16) -> ycomb_b (bf16)
  float* r1 = ws + 1*BLD;   // h1b (bf16)
  float* r2 = ws + 2*BLD;   // xz_b (bf16, BL x 512 = full region)
  float* r3 = ws + 3*BLD;   // xd (fp32 BLx64) -- live through fused_scan
  float* r4 = ws + 4*BLD;   // m1 (fp32 BLx128)
  float* r6 = ws + 6*BLD;   // wbuf1 (bf16 in_proj) -> H (Hout/Hin in place)
  float* r7 = ws + 7*BLD;   // wbuf2 (bf16 weights) + bar + S-plane (tail)

  unsigned short* h0b   = (unsigned short*)r0;
  unsigned short* h1b   = (unsigned short*)r1;
  unsigned short* xz_b  = (unsigned short*)r2;   // BL x XZS
  float*          xd    = r3;                    // BL x 64 fp32
  unsigned short* wbuf1 = (unsigned short*)r6;   // 131072 (512x256)
  float* H = r6;                                 // 2*CH*BB*DD*NST = BLD floats
  const size_t SPLANE = (size_t)2*CH*BB*DD;      // 524288 floats (2 MB)
  float* Sp   = r7 + (BLD - SPLANE);             // tail of r7
  unsigned* bar = (unsigned*)(Sp - 4);           // 2 barrier counters (free gap)
  unsigned short* ycomb_b = (unsigned short*)r0; // r0 free after xz gemm
  unsigned short* wbuf2   = (unsigned short*)r7;
  unsigned short* wb_xp   = wbuf2;               // 16384  (64x256)
  unsigned short* wb_out  = wbuf2 + 16384;       // 65536
  unsigned short* wb_fc1  = wbuf2 + 81920;       // 32768
  unsigned short* wb_fc2  = wbuf2 + 114688;      // 32768
  float*          m1      = r4;                  // BLx128 fp32

  // 1. pre: rms(x0)->h0b, rms(x1)->h1b, weight conversions, barrier init
  pre_kernel<<<dim3(9280), 256, 0, stream>>>(
      x0, w_norm0, h0b, x1, w_norm1, h1b,
      in_proj_w, xproj_w_f, xproj_w_bw, out_proj_w, fc1_w, fc2_w, wbuf1, wbuf2,
      bar);

  // 2. merged xz (N=512) + xproj (N=64) GEMM -- ONE dispatch
  gemm_xzxp<<<dim3(BL/64, 9), 256, 0, stream>>>(
      h0b, h1b, wbuf1, wb_xp, xz_b, xd);

  // 3. FUSED persistent scan: front + carry + back -> ycomb_b
  fused_scan<<<dim3(CH*BB), 256, 0, stream>>>(
      xz_b, xd, conv_w_f, conv_b_f, conv_w_bw, conv_b_bw,
      dtproj_w_f, dtproj_b_f, dtproj_w_bw, dtproj_b_bw,
      A_log_f, A_log_bw, D_f, D_bw, norm_y_w, ycomb_b, Sp, H, bar);

  // 4. x = y @ out_proj.T + residual(x0) -> d_out (fp32)
  gemm_mfma<2><<<dim3(BL/64, 4), 256, 0, stream>>>(
      ycomb_b, wb_out, out, x0, nullptr, BL, 256, 256);

  // 5. m1 = x @ fc1.T (A staged from fp32 out)
  gemm_fc1<<<dim3(BL/64, 2), 256, 0, stream>>>(out, wb_fc1, m1);

  // 6. out += silu(dwconv3(m1)) @ fc2.T  (dwconv fused into A-staging)
  gemm_fc2dw<<<dim3(BL/64, 4), 256, 0, stream>>>(m1, wb_fc2, dw_w, dw_b, out);
}

// Round 9
// 251.891 us; speedup vs baseline: 2.6602x; 2.6602x over previous
//
#include <hip/hip_runtime.h>
#include <math.h>
#include <cstddef>

#define BB 4
#define LL 4096
#define DD 256
#define NST 8
#define RANK 16
#define HID 128
#define BL (BB*LL)          // 16384
#define BLD ((size_t)BL*DD) // 4194304
#define CH 256              // scan chunks
#define CLEN 16             // steps per chunk (CH*CLEN == LL)
#define XZS 512             // xz row stride (xin cols 0..255, z cols 256..511)

typedef __bf16 bf16x8 __attribute__((ext_vector_type(8)));
typedef float  f32x4  __attribute__((ext_vector_type(4)));

__device__ __forceinline__ float siluf(float x){ return x / (1.f + __expf(-x)); }
__device__ __forceinline__ float softplus_fast(float x){
  float r = __logf(1.f + __expf(x));
  return x > 15.f ? x : r;
}
// fp32 -> bf16 bits, round-to-nearest-even
__device__ __forceinline__ unsigned short f2bf(float x){
  union { float f; unsigned u; } v; v.f = x;
  unsigned r = v.u + 0x7fffu + ((v.u >> 16) & 1u);
  return (unsigned short)(r >> 16);
}
__device__ __forceinline__ float bf2f(unsigned short u){
  union { unsigned u32; float f; } c; c.u32 = ((unsigned)u) << 16;
  return c.f;
}

// --- async global->LDS, 16B/lane (1KB/wave-instr), linear LDS dest -------------
#define GLD16(gp, lp) __builtin_amdgcn_global_load_lds( \
    (const __attribute__((address_space(1))) unsigned int*)(gp), \
    (__attribute__((address_space(3))) unsigned int*)(lp), 16, 0, 0)

// swizzled-granule read: logical (row, g16) -> granule row*8 + (g16 ^ (row&7)).
#define LDSG(base, row, gq) \
  (*(const bf16x8*)((base) + ((((row) << 3) + ((gq) ^ ((row) & 7))) << 3)))

// =============== Pre: RMSNorm (both streams) + weight cvt, ONE dispatch ==========
__global__ __launch_bounds__(256) void pre_kernel(
    const float* __restrict__ x0, const float* __restrict__ w0, unsigned short* __restrict__ o0b,
    const float* __restrict__ x1, const float* __restrict__ w1, unsigned short* __restrict__ o1b,
    const float* __restrict__ sA,
    const float* __restrict__ s0, const float* __restrict__ s1,
    const float* __restrict__ s2, const float* __restrict__ s3,
    const float* __restrict__ s4,
    unsigned short* __restrict__ d1, unsigned short* __restrict__ d2)
{
  int blk = blockIdx.x;
  if (blk < 8192){
    const float* x; const float* w; unsigned short* o; size_t tok;
    int wv = threadIdx.x >> 6, lane = threadIdx.x & 63;
    if (blk < 4096){ x = x0; w = w0; o = o0b; tok = (size_t)blk*4 + wv; }
    else           { x = x1; w = w1; o = o1b; tok = (size_t)(blk-4096)*4 + wv; }
    float4 v = ((const float4*)(x + tok*DD))[lane];
    float s = v.x*v.x + v.y*v.y + v.z*v.z + v.w*v.w;
    #pragma unroll
    for (int m = 1; m < 64; m <<= 1) s += __shfl_xor(s, m, 64);
    float scale = 1.f / (sqrtf(s) * (1.f/16.f) + 1e-6f);
    float4 wvv = ((const float4*)w)[lane];
    ushort4 r;
    r.x = f2bf(v.x*scale*wvv.x); r.y = f2bf(v.y*scale*wvv.y);
    r.z = f2bf(v.z*scale*wvv.z); r.w = f2bf(v.w*scale*wvv.w);
    ((ushort4*)(o + tok*DD))[lane] = r;
    return;
  }
  int i = (blk - 8192)*256 + threadIdx.x;   // 0..278527
  if (i >= 278528) return;
  if (i < 131072){ d1[i] = f2bf(sA[i]); return; }
  int j = i - 131072;
  float v;
  if (j < 8192)        v = s0[j];
  else if (j < 16384)  v = s1[j - 8192];
  else if (j < 81920)  v = s2[j - 16384];
  else if (j < 114688) v = s3[j - 81920];
  else                 v = s4[j - 114688];
  d2[j] = f2bf(v);
}

// ---------------- bf16 MFMA GEMM, 64x64 tile, BK=64, global_load_lds staging -----
// EPI: 0 = C=acc ; 2 = C=acc+Add ; 3 = Cb=bf16(acc)
template<int EPI>
__global__ __launch_bounds__(256) void gemm_mfma(
    const unsigned short* __restrict__ A, const unsigned short* __restrict__ Bw,
    float* __restrict__ C, const float* __restrict__ Add,
    unsigned short* __restrict__ Cb, int M, int ldc, int K)
{
  constexpr int BK = 64;
  __shared__ __align__(16) unsigned short AsL[64*64];
  __shared__ __align__(16) unsigned short BsL[64*64];
  int tid  = threadIdx.x;
  int row0 = blockIdx.x * 64;
  int col0 = blockIdx.y * 64;
  int wave = tid >> 6, lane = tid & 63;
  int wm = (wave >> 1) * 32, wn = (wave & 1) * 32;
  int lm = lane & 15, kq = lane >> 4;

  int q0 = wave*128 + lane, q1 = q0 + 64;
  int ra = q0 >> 3, ga = (q0 & 7) ^ (ra & 7);
  int rb = q1 >> 3, gb = (q1 & 7) ^ (rb & 7);
  const unsigned short* A0 = A  + (size_t)(row0 + ra)*K + ga*8;
  const unsigned short* A1 = A  + (size_t)(row0 + rb)*K + gb*8;
  const unsigned short* B0 = Bw + (size_t)(col0 + ra)*K + ga*8;
  const unsigned short* B1 = Bw + (size_t)(col0 + rb)*K + gb*8;
  unsigned short* lA0 = AsL + wave*1024;
  unsigned short* lB0 = BsL + wave*1024;

  f32x4 acc[2][2];
  #pragma unroll
  for (int i = 0; i < 2; i++)
    #pragma unroll
    for (int j = 0; j < 2; j++) acc[i][j] = (f32x4){0.f,0.f,0.f,0.f};

  for (int k0 = 0; k0 < K; k0 += BK){
    GLD16(A0 + k0, lA0);       GLD16(A1 + k0, lA0 + 512);
    GLD16(B0 + k0, lB0);       GLD16(B1 + k0, lB0 + 512);
    __syncthreads();
    #pragma unroll
    for (int ks = 0; ks < 2; ks++){
      bf16x8 af[2], bfv[2];
      #pragma unroll
      for (int i = 0; i < 2; i++) af[i]  = LDSG(AsL, wm + i*16 + lm, ks*4 + kq);
      #pragma unroll
      for (int j = 0; j < 2; j++) bfv[j] = LDSG(BsL, wn + j*16 + lm, ks*4 + kq);
      #pragma unroll
      for (int i = 0; i < 2; i++)
        #pragma unroll
        for (int j = 0; j < 2; j++)
          acc[i][j] = __builtin_amdgcn_mfma_f32_16x16x32_bf16(af[i], bfv[j], acc[i][j], 0, 0, 0);
    }
    __syncthreads();
  }

  #pragma unroll
  for (int i = 0; i < 2; i++){
    int rbase = row0 + wm + i*16 + kq*4;
    #pragma unroll
    for (int j = 0; j < 2; j++){
      int col = col0 + wn + j*16 + lm;
      #pragma unroll
      for (int r = 0; r < 4; r++){
        size_t idx = (size_t)(rbase + r)*ldc + col;
        float v = acc[i][j][r];
        if constexpr (EPI == 2) v += Add[idx];
        if constexpr (EPI != 3) C[idx] = v;
        if constexpr (EPI == 3) Cb[idx] = f2bf(v);
      }
    }
  }
}

// =============== Merged xz + xproj GEMM (gload_lds staging) ======================
__global__ __launch_bounds__(256) void gemm_xzxp(
    const unsigned short* __restrict__ A0i, const unsigned short* __restrict__ A1i,
    const unsigned short* __restrict__ B0i, const unsigned short* __restrict__ B1i,
    unsigned short* __restrict__ Cxz, float* __restrict__ Cxd)
{
  constexpr int BK = 64, K = 256;
  __shared__ __align__(16) unsigned short AsL[64*64];
  __shared__ __align__(16) unsigned short BsL[64*64];
  int tid  = threadIdx.x;
  bool xp  = (blockIdx.y == 8);
  const unsigned short* A  = xp ? A1i : A0i;
  const unsigned short* Bw = xp ? B1i : B0i;
  int row0 = blockIdx.x * 64;
  int col0 = xp ? 0 : blockIdx.y * 64;
  int wave = tid >> 6, lane = tid & 63;
  int wm = (wave >> 1) * 32, wn = (wave & 1) * 32;
  int lm = lane & 15, kq = lane >> 4;

  int q0 = wave*128 + lane, q1 = q0 + 64;
  int ra = q0 >> 3, ga = (q0 & 7) ^ (ra & 7);
  int rb = q1 >> 3, gb = (q1 & 7) ^ (rb & 7);
  const unsigned short* A0 = A  + (size_t)(row0 + ra)*K + ga*8;
  const unsigned short* A1 = A  + (size_t)(row0 + rb)*K + gb*8;
  const unsigned short* B0 = Bw + (size_t)(col0 + ra)*K + ga*8;
  const unsigned short* B1 = Bw + (size_t)(col0 + rb)*K + gb*8;
  unsigned short* lA0 = AsL + wave*1024;
  unsigned short* lB0 = BsL + wave*1024;

  f32x4 acc[2][2];
  #pragma unroll
  for (int i = 0; i < 2; i++)
    #pragma unroll
    for (int j = 0; j < 2; j++) acc[i][j] = (f32x4){0.f,0.f,0.f,0.f};

  for (int k0 = 0; k0 < K; k0 += BK){
    GLD16(A0 + k0, lA0);       GLD16(A1 + k0, lA0 + 512);
    GLD16(B0 + k0, lB0);       GLD16(B1 + k0, lB0 + 512);
    __syncthreads();
    #pragma unroll
    for (int ks = 0; ks < 2; ks++){
      bf16x8 af[2], bfv[2];
      #pragma unroll
      for (int i = 0; i < 2; i++) af[i]  = LDSG(AsL, wm + i*16 + lm, ks*4 + kq);
      #pragma unroll
      for (int j = 0; j < 2; j++) bfv[j] = LDSG(BsL, wn + j*16 + lm, ks*4 + kq);
      #pragma unroll
      for (int i = 0; i < 2; i++)
        #pragma unroll
        for (int j = 0; j < 2; j++)
          acc[i][j] = __builtin_amdgcn_mfma_f32_16x16x32_bf16(af[i], bfv[j], acc[i][j], 0, 0, 0);
    }
    __syncthreads();
  }

  #pragma unroll
  for (int i = 0; i < 2; i++){
    int rbase = row0 + wm + i*16 + kq*4;
    #pragma unroll
    for (int j = 0; j < 2; j++){
      int col = col0 + wn + j*16 + lm;
      #pragma unroll
      for (int r = 0; r < 4; r++){
        float v = acc[i][j][r];
        if (xp) Cxd[(size_t)(rbase + r)*64  + col] = v;
        else    Cxz[(size_t)(rbase + r)*XZS + col] = f2bf(v);
      }
    }
  }
}

// =============== fc1: fp32-A GEMM (A padded-LDS convert; B gload_lds) ============
__global__ __launch_bounds__(256) void gemm_fc1(
    const float* __restrict__ A, const unsigned short* __restrict__ Bw,
    float* __restrict__ C)
{
  constexpr int BK = 64, PAD = 8, K = 256, LDC = 128;
  __shared__ __align__(16) unsigned short As[64][BK+PAD];
  __shared__ __align__(16) unsigned short BsL[64*64];
  int tid  = threadIdx.x;
  int row0 = blockIdx.x * 64;
  int col0 = blockIdx.y * 64;
  int wave = tid >> 6, lane = tid & 63;
  int wm = (wave >> 1) * 32, wn = (wave & 1) * 32;
  int lm = lane & 15, kq = lane >> 4;
  int sr = tid >> 2, sc16 = (tid & 3) * 16;

  int q0 = wave*128 + lane, q1 = q0 + 64;
  int ra = q0 >> 3, ga = (q0 & 7) ^ (ra & 7);
  int rb = q1 >> 3, gb = (q1 & 7) ^ (rb & 7);
  const unsigned short* B0 = Bw + (size_t)(col0 + ra)*K + ga*8;
  const unsigned short* B1 = Bw + (size_t)(col0 + rb)*K + gb*8;
  unsigned short* lB0 = BsL + wave*1024;

  f32x4 acc[2][2];
  #pragma unroll
  for (int i = 0; i < 2; i++)
    #pragma unroll
    for (int j = 0; j < 2; j++) acc[i][j] = (f32x4){0.f,0.f,0.f,0.f};

  for (int k0 = 0; k0 < K; k0 += BK){
    GLD16(B0 + k0, lB0);       GLD16(B1 + k0, lB0 + 512);
    const float* ap = &A[(size_t)(row0 + sr)*K + k0 + sc16];
    #pragma unroll
    for (int q = 0; q < 4; q++){
      float4 f = *(const float4*)(ap + q*4);
      ushort4 u; u.x = f2bf(f.x); u.y = f2bf(f.y); u.z = f2bf(f.z); u.w = f2bf(f.w);
      *(ushort4*)&As[sr][sc16 + q*4] = u;
    }
    __syncthreads();
    #pragma unroll
    for (int ks = 0; ks < 2; ks++){
      bf16x8 af[2], bfv[2];
      #pragma unroll
      for (int i = 0; i < 2; i++) af[i]  = *(const bf16x8*)&As[wm + i*16 + lm][ks*32 + kq*8];
      #pragma unroll
      for (int j = 0; j < 2; j++) bfv[j] = LDSG(BsL, wn + j*16 + lm, ks*4 + kq);
      #pragma unroll
      for (int i = 0; i < 2; i++)
        #pragma unroll
        for (int j = 0; j < 2; j++)
          acc[i][j] = __builtin_amdgcn_mfma_f32_16x16x32_bf16(af[i], bfv[j], acc[i][j], 0, 0, 0);
    }
    __syncthreads();
  }

  #pragma unroll
  for (int i = 0; i < 2; i++){
    int rbase = row0 + wm + i*16 + kq*4;
    #pragma unroll
    for (int j = 0; j < 2; j++){
      int col = col0 + wn + j*16 + lm;
      #pragma unroll
      for (int r = 0; r < 4; r++)
        C[(size_t)(rbase + r)*LDC + col] = acc[i][j][r];
    }
  }
}

// =============== fc2 with dwconv+silu fused into A-staging (B gload_lds) =========
__global__ __launch_bounds__(256) void gemm_fc2dw(
    const float* __restrict__ m1, const unsigned short* __restrict__ Bw,
    const float* __restrict__ dww, const float* __restrict__ dwb,
    float* __restrict__ C)
{
  constexpr int BK = 64, PAD = 8, K = 128, LDC = 256;
  __shared__ __align__(16) unsigned short As[64][BK+PAD];
  __shared__ __align__(16) unsigned short BsL[64*64];
  __shared__ float wS[HID*3];
  __shared__ float bS[HID];
  int tid  = threadIdx.x;
  if (tid < HID){
    bS[tid] = dwb[tid];
    wS[tid*3+0] = dww[tid*3+0];
    wS[tid*3+1] = dww[tid*3+1];
    wS[tid*3+2] = dww[tid*3+2];
  }
  __syncthreads();

  int row0 = blockIdx.x * 64;
  int col0 = blockIdx.y * 64;
  int wave = tid >> 6, lane = tid & 63;
  int wm = (wave >> 1) * 32, wn = (wave & 1) * 32;
  int lm = lane & 15, kq = lane >> 4;
  int r16 = tid >> 4, cc = (tid & 15) * 4;

  int q0 = wave*128 + lane, q1 = q0 + 64;
  int ra = q0 >> 3, ga = (q0 & 7) ^ (ra & 7);
  int rb = q1 >> 3, gb = (q1 & 7) ^ (rb & 7);
  const unsigned short* B0 = Bw + (size_t)(col0 + ra)*K + ga*8;
  const unsigned short* B1 = Bw + (size_t)(col0 + rb)*K + gb*8;
  unsigned short* lB0 = BsL + wave*1024;

  f32x4 acc[2][2];
  #pragma unroll
  for (int i = 0; i < 2; i++)
    #pragma unroll
    for (int j = 0; j < 2; j++) acc[i][j] = (f32x4){0.f,0.f,0.f,0.f};

  for (int k0 = 0; k0 < K; k0 += BK){
    GLD16(B0 + k0, lB0);       GLD16(B1 + k0, lB0 + 512);
    #pragma unroll
    for (int pp = 0; pp < 4; pp++){
      int r = pp*16 + r16;
      int t = row0 + r;
      int tl = t & (LL-1);
      int c = k0 + cc;
      const float* mrow = &m1[(size_t)t*HID + c];
      float4 vm = *(const float4*)mrow;
      float4 vp = (tl > 0)      ? *(const float4*)(mrow - HID) : (float4){0,0,0,0};
      float4 vn = (tl < LL-1)   ? *(const float4*)(mrow + HID) : (float4){0,0,0,0};
      float a0 = bS[c+0] + wS[(c+0)*3]*vp.x + wS[(c+0)*3+1]*vm.x + wS[(c+0)*3+2]*vn.x;
      float a1 = bS[c+1] + wS[(c+1)*3]*vp.y + wS[(c+1)*3+1]*vm.y + wS[(c+1)*3+2]*vn.y;
      float a2 = bS[c+2] + wS[(c+2)*3]*vp.z + wS[(c+2)*3+1]*vm.z + wS[(c+2)*3+2]*vn.z;
      float a3 = bS[c+3] + wS[(c+3)*3]*vp.w + wS[(c+3)*3+1]*vm.w + wS[(c+3)*3+2]*vn.w;
      ushort4 u;
      u.x = f2bf(siluf(a0)); u.y = f2bf(siluf(a1));
      u.z = f2bf(siluf(a2)); u.w = f2bf(siluf(a3));
      *(ushort4*)&As[r][cc] = u;
    }
    __syncthreads();
    #pragma unroll
    for (int ks = 0; ks < 2; ks++){
      bf16x8 af[2], bfv[2];
      #pragma unroll
      for (int i = 0; i < 2; i++) af[i]  = *(const bf16x8*)&As[wm + i*16 + lm][ks*32 + kq*8];
      #pragma unroll
      for (int j = 0; j < 2; j++) bfv[j] = LDSG(BsL, wn + j*16 + lm, ks*4 + kq);
      #pragma unroll
      for (int i = 0; i < 2; i++)
        #pragma unroll
        for (int j = 0; j < 2; j++)
          acc[i][j] = __builtin_amdgcn_mfma_f32_16x16x32_bf16(af[i], bfv[j], acc[i][j], 0, 0, 0);
    }
    __syncthreads();
  }

  #pragma unroll
  for (int i = 0; i < 2; i++){
    int rbase = row0 + wm + i*16 + kq*4;
    #pragma unroll
    for (int j = 0; j < 2; j++){
      int col = col0 + wn + j*16 + lm;
      #pragma unroll
      for (int r = 0; r < 4; r++){
        size_t idx = (size_t)(rbase + r)*LDC + col;
        C[idx] = C[idx] + acc[i][j][r];
      }
    }
  }
}

// =================== Front: conv+silu+delta + local scan w/ C-apply ==============
// MEASURED-BEST BODY (split-phase + dA*=e1 chain; known-bad: merged loop 67us,
// e-tree 54us). r9 change is GEOMETRY ONLY (positive track record: r1 CH
// 128->256 = 51->43.6us): d-range split across 2 blocks of 128 threads
// (blockIdx.y = b*2 + dhalf) -> 2x resident waves for latency hiding. Per-thread
// instruction stream identical; only the LDS stage loop strides by 128
// (same 1KB tile staged in both dhalf blocks, negligible duplicate).
__global__ __launch_bounds__(128) void front_kernel(
    const unsigned short* __restrict__ xz,
    const float* __restrict__ xd,
    const float* __restrict__ cwf, const float* __restrict__ cbf,
    const float* __restrict__ cwb, const float* __restrict__ cbb,
    const float* __restrict__ dtwf, const float* __restrict__ dtbf,
    const float* __restrict__ dtwb, const float* __restrict__ dtbb,
    const float* __restrict__ Alogf, const float* __restrict__ Alogb,
    const float* __restrict__ Dfp, const float* __restrict__ Dbp,
    unsigned int* __restrict__ xde,
    float* __restrict__ Sp, float* __restrict__ Hout)
{
  int chunk = blockIdx.x;
  int b     = blockIdx.y >> 1;
  int dh    = blockIdx.y & 1;
  int dir   = blockIdx.z;
  int s0 = chunk*CLEN;
  int d  = dh*128 + threadIdx.x;

  __shared__ float sdt[CLEN][16];   // 1 KB
  __shared__ float sB [CLEN][8];    // 0.5 KB
  __shared__ float sC [CLEN][8];    // 0.5 KB
  #pragma unroll
  for (int e = threadIdx.x; e < CLEN*32; e += 128){
    int lt = e >> 5, col = e & 31;
    int pos = s0 + lt;
    int row = dir ? (LL-1-pos) : pos;
    float v = xd[((size_t)b*LL + row)*64 + dir*32 + col];
    if (col < 16)      sdt[lt][col]    = v;
    else if (col < 24) sB [lt][col-16] = v;
    else               sC [lt][col-24] = v;
  }
  __syncthreads();

  float4 cw = ((const float4*)(dir ? cwb : cwf))[d];
  float cb  = (dir ? cbb : cbf)[d];
  const float* dtw = (dir ? dtwb : dtwf) + d*RANK;
  float4 w0 = ((const float4*)dtw)[0], w1 = ((const float4*)dtw)[1];
  float4 w2 = ((const float4*)dtw)[2], w3 = ((const float4*)dtw)[3];
  float dtb = (dir ? dtbb : dtbf)[d];
  float Dd  = (dir ? Dbp : Dfp)[d];

  const unsigned short* xp = xz + (size_t)b*LL*XZS + d;
  #define LDX(pos) ((pos) >= 0 ? bf2f(xp[(size_t)(dir ? (LL-1-(pos)) : (pos))*XZS]) : 0.f)

  // ---- phase 1: conv + silu + delta, packed into regs (full ILP) ----
  float xv[CLEN+3];
  xv[0] = LDX(s0-3); xv[1] = LDX(s0-2); xv[2] = LDX(s0-1);
  #pragma unroll
  for (int i = 0; i < CLEN; i++) xv[3+i] = LDX(s0+i);
  #undef LDX

  unsigned packX[CLEN];
  #pragma unroll
  for (int i = 0; i < CLEN; i++){
    float xc = cb;
    xc = fmaf(cw.x, xv[i],   xc); xc = fmaf(cw.y, xv[i+1], xc);
    xc = fmaf(cw.z, xv[i+2], xc); xc = fmaf(cw.w, xv[i+3], xc);
    xc = siluf(xc);
    const float* dt = &sdt[i][0];
    float de = dtb;
    de = fmaf(dt[0],w0.x, fmaf(dt[1],w0.y, fmaf(dt[2],w0.z, fmaf(dt[3],w0.w, de))));
    de = fmaf(dt[4],w1.x, fmaf(dt[5],w1.y, fmaf(dt[6],w1.z, fmaf(dt[7],w1.w, de))));
    de = fmaf(dt[8],w2.x, fmaf(dt[9],w2.y, fmaf(dt[10],w2.z, fmaf(dt[11],w2.w, de))));
    de = fmaf(dt[12],w3.x, fmaf(dt[13],w3.y, fmaf(dt[14],w3.z, fmaf(dt[15],w3.w, de))));
    de = softplus_fast(de);
    packX[i] = (unsigned)f2bf(xc) | ((unsigned)f2bf(de) << 16);
  }

  // ---- phase 2: local scan (h from 0) with C-apply; write pack (y0,de) ----
  const float* Alog = dir ? Alogb : Alogf;
  float A[NST];
  bool fast = true;
  #pragma unroll
  for (int n = 0; n < NST; n++){
    A[n] = -__expf(Alog[d*NST + n]);
    fast = fast && (fabsf(A[n] + (float)(n+1)) < 1e-3f);
  }
  float h[NST];
  #pragma unroll
  for (int n = 0; n < NST; n++) h[n] = 0.f;
  float S = 0.f;

  unsigned int* xout = xde + ((size_t)(dir*BB + b)*LL + s0)*DD + d;

  if (fast){
    #pragma unroll
    for (int t = 0; t < CLEN; t++){
      unsigned pk = packX[t];
      float xc = bf2f((unsigned short)(pk & 0xffffu));
      float de = bf2f((unsigned short)(pk >> 16));
      S += de;
      float dux = de * xc;
      const float* Bv = &sB[t][0];
      const float* Cv = &sC[t][0];
      float e1 = __expf(-de);
      float dA = e1;
      float acc = xc * Dd;
      h[0] = fmaf(dA, h[0], dux*Bv[0]); acc = fmaf(h[0], Cv[0], acc); dA *= e1;
      h[1] = fmaf(dA, h[1], dux*Bv[1]); acc = fmaf(h[1], Cv[1], acc); dA *= e1;
      h[2] = fmaf(dA, h[2], dux*Bv[2]); acc = fmaf(h[2], Cv[2], acc); dA *= e1;
      h[3] = fmaf(dA, h[3], dux*Bv[3]); acc = fmaf(h[3], Cv[3], acc); dA *= e1;
      h[4] = fmaf(dA, h[4], dux*Bv[4]); acc = fmaf(h[4], Cv[4], acc); dA *= e1;
      h[5] = fmaf(dA, h[5], dux*Bv[5]); acc = fmaf(h[5], Cv[5], acc); dA *= e1;
      h[6] = fmaf(dA, h[6], dux*Bv[6]); acc = fmaf(h[6], Cv[6], acc); dA *= e1;
      h[7] = fmaf(dA, h[7], dux*Bv[7]); acc = fmaf(h[7], Cv[7], acc);
      xout[(size_t)t*DD] = (pk & 0xffff0000u) | (unsigned)f2bf(acc);
    }
  } else {
    #pragma unroll
    for (int t = 0; t < CLEN; t++){
      unsigned pk = packX[t];
      float xc = bf2f((unsigned short)(pk & 0xffffu));
      float de = bf2f((unsigned short)(pk >> 16));
      S += de;
      float dux = de * xc;
      const float* Bv = &sB[t][0];
      const float* Cv = &sC[t][0];
      float acc = xc * Dd;
      #pragma unroll
      for (int n = 0; n < NST; n++){
        h[n] = fmaf(__expf(de*A[n]), h[n], dux*Bv[n]);
        acc = fmaf(h[n], Cv[n], acc);
      }
      xout[(size_t)t*DD] = (pk & 0xffff0000u) | (unsigned)f2bf(acc);
    }
  }

  size_t ob = ((((size_t)dir*CH + chunk)*BB + b)*DD + d)*NST;
  float4 h0v, h1v;
  h0v.x=h[0]; h0v.y=h[1]; h0v.z=h[2]; h0v.w=h[3];
  h1v.x=h[4]; h1v.y=h[5]; h1v.z=h[6]; h1v.w=h[7];
  *(float4*)&Hout[ob]   = h0v; *(float4*)&Hout[ob+4] = h1v;
  Sp[((size_t)(dir*CH + chunk)*BB + b)*DD + d] = S;
}

// Phase 2: chunk-carry scan, 2-level. Block = (dir,b,d) -> 2048 one-wave blocks.
__global__ __launch_bounds__(64) void scan_p2(
    const float* __restrict__ Sp, float* H,
    const float* __restrict__ Alogf, const float* __restrict__ Alogb)
{
  const int SEGC = CH/8;    // 32 chunks per segment
  int blk = blockIdx.x;
  int d   = blk & (DD-1);
  int b   = (blk >> 8) & (BB-1);
  int dir = blk >> 10;
  int t   = threadIdx.x;
  int seg = t >> 3, n = t & 7;
  float A = -__expf((dir ? Alogb : Alogf)[d*NST + n]);

  const size_t sstr = (size_t)BB*DD;          // per-chunk stride in Sp
  const size_t hstr = (size_t)BB*DD*NST;      // per-chunk stride in H
  size_t sb = (size_t)dir*CH*sstr + (size_t)b*DD + d;
  size_t hb = (size_t)dir*CH*hstr + ((size_t)b*DD + d)*NST + n;
  int c0 = seg*SEGC;

  float pv[SEGC], hv[SEGC];
  #pragma unroll
  for (int k = 0; k < SEGC; k++){
    pv[k] = Sp[sb + (size_t)(c0+k)*sstr];
    hv[k] = H [hb + (size_t)(c0+k)*hstr];
  }
  float h = 0.f, Ss = 0.f;
  #pragma unroll
  for (int k = 0; k < SEGC; k++){
    Ss += pv[k];
    pv[k] = __expf(pv[k]*A);
    h = fmaf(pv[k], h, hv[k]);
  }
  float pi = __expf(Ss*A), hi = h;
  #pragma unroll
  for (int off = 8; off < 64; off <<= 1){
    float hprev = __shfl_up(hi, off, 64);
    float pprev = __shfl_up(pi, off, 64);
    if (t >= off){ hi = fmaf(pi, hprev, hi); pi *= pprev; }
  }
  float hin = __shfl_up(hi, 8, 64);
  h = (seg == 0) ? 0.f : hin;
  #pragma unroll
  for (int k = 0; k < SEGC; k++){
    size_t idx = hb + (size_t)(c0+k)*hstr;
    H[idx] = h;
    h = fmaf(pv[k], h, hv[k]);
  }
}

// =================== Back: correction + combine + rmsnorm + gate ==================
// Serial q*=E chain (measured-best; the E-tree variant regressed via VGPR).
__global__ __launch_bounds__(256) void back_kernel(
    const unsigned int* __restrict__ xde,
    const float* __restrict__ xd,
    const float* __restrict__ Alogf, const float* __restrict__ Alogb,
    const float* __restrict__ Hin,
    const unsigned short* __restrict__ xz,
    const float* __restrict__ wn,
    unsigned short* __restrict__ outb)
{
  int c  = blockIdx.x, b = blockIdx.y;
  int cbk = CH-1-c;
  int d  = threadIdx.x;
  int T0 = c*CLEN;          // token base (fwd storage base)
  int Pb = cbk*CLEN;        // bwd storage base; storage Pb+k <-> token T0+15-k

  __shared__ float sCf[CLEN][8], sCb[CLEN][8];  // 1 KB
  __shared__ float red[CLEN][4];
  __shared__ float sscale[CLEN];
  {
    int k  = threadIdx.x & 7;
    int lt = (threadIdx.x >> 3) & 15;
    if (threadIdx.x < 128)
      sCf[lt][k] = xd[((size_t)b*LL + T0 + lt)*64 + 24 + k];
    else
      sCb[lt][k] = xd[((size_t)b*LL + (T0 + 15 - lt))*64 + 56 + k];
  }
  __syncthreads();

  float Af[NST], Ab[NST];
  bool fast = true;
  #pragma unroll
  for (int n = 0; n < NST; n++){
    Af[n] = -__expf(Alogf[d*NST + n]);
    Ab[n] = -__expf(Alogb[d*NST + n]);
    fast = fast && (fabsf(Af[n] + (float)(n+1)) < 1e-3f)
                && (fabsf(Ab[n] + (float)(n+1)) < 1e-3f);
  }

  float vf[CLEN];

  // ---- forward correction ----
  {
    float hn[NST];
    size_t ib = (((size_t)c*BB + b)*DD + d)*NST;                 // dir=0
    float4 a0 = *(const float4*)&Hin[ib];
    float4 a1 = *(const float4*)&Hin[ib+4];
    hn[0]=a0.x; hn[1]=a0.y; hn[2]=a0.z; hn[3]=a0.w;
    hn[4]=a1.x; hn[5]=a1.y; hn[6]=a1.z; hn[7]=a1.w;
    const unsigned int* p = xde + ((size_t)b*LL + T0)*DD + d;    // dir=0 plane
    unsigned int pk[CLEN];
    #pragma unroll
    for (int t = 0; t < CLEN; t++) pk[t] = p[(size_t)t*DD];
    float S = 0.f;
    if (fast){
      #pragma unroll
      for (int t = 0; t < CLEN; t++){
        float y0 = bf2f((unsigned short)(pk[t] & 0xffffu));
        float de = bf2f((unsigned short)(pk[t] >> 16));
        S += de;
        float E = __expf(-S);
        float q = E;
        float corr = q * (hn[0]*sCf[t][0]);
        q *= E; corr = fmaf(q, hn[1]*sCf[t][1], corr);
        q *= E; corr = fmaf(q, hn[2]*sCf[t][2], corr);
        q *= E; corr = fmaf(q, hn[3]*sCf[t][3], corr);
        q *= E; corr = fmaf(q, hn[4]*sCf[t][4], corr);
        q *= E; corr = fmaf(q, hn[5]*sCf[t][5], corr);
        q *= E; corr = fmaf(q, hn[6]*sCf[t][6], corr);
        q *= E; corr = fmaf(q, hn[7]*sCf[t][7], corr);
        vf[t] = y0 + corr;
      }
    } else {
      #pragma unroll
      for (int t = 0; t < CLEN; t++){
        float y0 = bf2f((unsigned short)(pk[t] & 0xffffu));
        float de = bf2f((unsigned short)(pk[t] >> 16));
        S += de;
        float corr = 0.f;
        #pragma unroll
        for (int n = 0; n < NST; n++)
          corr = fmaf(__expf(S*Af[n]), hn[n]*sCf[t][n], corr);
        vf[t] = y0 + corr;
      }
    }
  }

  // ---- backward correction, merged into vf (token j pairs with bwd k=15-j) ----
  {
    float hn[NST];
    size_t ib = ((((size_t)CH + cbk)*BB + b)*DD + d)*NST;        // dir=1
    float4 a0 = *(const float4*)&Hin[ib];
    float4 a1 = *(const float4*)&Hin[ib+4];
    hn[0]=a0.x; hn[1]=a0.y; hn[2]=a0.z; hn[3]=a0.w;
    hn[4]=a1.x; hn[5]=a1.y; hn[6]=a1.z; hn[7]=a1.w;
    const unsigned int* p = xde + ((size_t)(BB + b)*LL + Pb)*DD + d;  // dir=1 plane
    unsigned int pk[CLEN];
    #pragma unroll
    for (int t = 0; t < CLEN; t++) pk[t] = p[(size_t)t*DD];
    float S = 0.f;
    if (fast){
      #pragma unroll
      for (int t = 0; t < CLEN; t++){
        float y0 = bf2f((unsigned short)(pk[t] & 0xffffu));
        float de = bf2f((unsigned short)(pk[t] >> 16));
        S += de;
        float E = __expf(-S);
        float q = E;
        float corr = q * (hn[0]*sCb[t][0]);
        q *= E; corr = fmaf(q, hn[1]*sCb[t][1], corr);
        q *= E; corr = fmaf(q, hn[2]*sCb[t][2], corr);
        q *= E; corr = fmaf(q, hn[3]*sCb[t][3], corr);
        q *= E; corr = fmaf(q, hn[4]*sCb[t][4], corr);
        q *= E; corr = fmaf(q, hn[5]*sCb[t][5], corr);
        q *= E; corr = fmaf(q, hn[6]*sCb[t][6], corr);
        q *= E; corr = fmaf(q, hn[7]*sCb[t][7], corr);
        int j = 15 - t;
        vf[j] = 0.5f*(vf[j] + y0 + corr);
      }
    } else {
      #pragma unroll
      for (int t = 0; t < CLEN; t++){
        float y0 = bf2f((unsigned short)(pk[t] & 0xffffu));
        float de = bf2f((unsigned short)(pk[t] >> 16));
        S += de;
        float corr = 0.f;
        #pragma unroll
        for (int n = 0; n < NST; n++)
          corr = fmaf(__expf(S*Ab[n]), hn[n]*sCb[t][n], corr);
        int j = 15 - t;
        vf[j] = 0.5f*(vf[j] + y0 + corr);
      }
    }
  }

  // ---- per-token RMS reduce over d ----
  int wave = d >> 6, lane = d & 63;
  #pragma unroll
  for (int j = 0; j < CLEN; j++){
    float s = vf[j]*vf[j];
    #pragma unroll
    for (int m = 1; m < 64; m <<= 1) s += __shfl_xor(s, m, 64);
    if (lane == 0) red[j][wave] = s;
  }
  __syncthreads();
  if (d < CLEN){
    float s = red[d][0] + red[d][1] + red[d][2] + red[d][3];
    sscale[d] = 1.f / (sqrtf(s)*(1.f/16.f) + 1e-6f);
  }
  __syncthreads();

  float wd = wn[d];
  #pragma unroll
  for (int j = 0; j < CLEN; j++){
    size_t tok = (size_t)b*LL + T0 + j;
    float z = bf2f(xz[tok*XZS + 256 + d]);
    outb[tok*DD + d] = f2bf(vf[j]*sscale[j]*wd*siluf(z));
  }
}

extern "C" void kernel_launch(void* const* d_in, const int* in_sizes, int n_in,
                              void* d_out, int out_size, void* d_ws, size_t ws_size,
                              hipStream_t stream)
{
  const float* x0        = (const float*)d_in[0];
  const float* x1        = (const float*)d_in[1];
  const float* w_norm0   = (const float*)d_in[2];
  const float* w_norm1   = (const float*)d_in[3];
  const float* in_proj_w = (const float*)d_in[4];
  const float* conv_w_f  = (const float*)d_in[5];
  const float* conv_b_f  = (const float*)d_in[6];
  const float* xproj_w_f = (const float*)d_in[7];
  const float* dtproj_w_f= (const float*)d_in[8];
  const float* dtproj_b_f= (const float*)d_in[9];
  const float* A_log_f   = (const float*)d_in[10];
  const float* D_f       = (const float*)d_in[11];
  const float* conv_w_bw = (const float*)d_in[12];
  const float* conv_b_bw = (const float*)d_in[13];
  const float* xproj_w_bw= (const float*)d_in[14];
  const float* dtproj_w_bw=(const float*)d_in[15];
  const float* dtproj_b_bw=(const float*)d_in[16];
  const float* A_log_bw  = (const float*)d_in[17];
  const float* D_bw      = (const float*)d_in[18];
  const float* norm_y_w  = (const float*)d_in[19];
  const float* out_proj_w= (const float*)d_in[20];
  const float* fc1_w     = (const float*)d_in[21];
  const float* dw_w      = (const float*)d_in[22];
  const float* dw_b      = (const float*)d_in[23];
  const float* fc2_w     = (const float*)d_in[24];
  float* out = (float*)d_out;
  float* ws  = (float*)d_ws;

  // region map (floats, BLD each), lifetime-reused
  float* r0 = ws + 0*BLD;   // h0b (bf16) -> ycomb_b (bf16)
  float* r1 = ws + 1*BLD;   // h1b (bf16)
  float* r2 = ws + 2*BLD;   // xz_b (bf16, BL x 512 = full region)
  float* r3 = ws + 3*BLD;   // xd (fp32 BLx64) -- live through back_kernel
  float* r4 = ws + 4*BLD;   // xde pack (y0,de) (uint32, spans r4+r5) -> m1 (fp32)
  float* r5 = ws + 5*BLD;
  float* r6 = ws + 6*BLD;   // wbuf1 (bf16 in_proj) -> Hout (= Hin, in-place p2)
  float* r7 = ws + 7*BLD;   // wbuf2 (bf16 weights) + S-plane (tail)

  unsigned short* h0b   = (unsigned short*)r0;
  unsigned short* h1b   = (unsigned short*)r1;
  unsigned short* xz_b  = (unsigned short*)r2;   // BL x XZS
  float*          xd    = r3;                    // BL x 64 fp32
  unsigned int*   xde   = (unsigned int*)r4;     // 2*BLD dwords = r4+r5
  unsigned short* wbuf1 = (unsigned short*)r6;   // 131072 (512x256)
  float* Hout = r6;                              // 2*CH*BB*DD*NST = BLD floats
  float* Hin  = Hout;                            // p2 rewrites in place
  const size_t SPLANE = (size_t)2*CH*BB*DD;      // 524288 floats (2 MB)
  float* Sp   = r7 + (BLD - SPLANE);             // tail of r7 (disjoint from wbuf2)
  unsigned short* ycomb_b = (unsigned short*)r0; // r0 free after xz gemm (h0b dead)
  unsigned short* wbuf2   = (unsigned short*)r7;
  unsigned short* wb_xp   = wbuf2;               // 16384  (64x256)
  unsigned short* wb_out  = wbuf2 + 16384;       // 65536
  unsigned short* wb_fc1  = wbuf2 + 81920;       // 32768
  unsigned short* wb_fc2  = wbuf2 + 114688;      // 32768
  float*          m1      = r4;                  // BLx128 fp32 (xde dead by then)

  // 1. pre: rms(x0)->h0b, rms(x1)->h1b, weight conversions -- ONE dispatch
  pre_kernel<<<dim3(9280), 256, 0, stream>>>(
      x0, w_norm0, h0b, x1, w_norm1, h1b,
      in_proj_w, xproj_w_f, xproj_w_bw, out_proj_w, fc1_w, fc2_w, wbuf1, wbuf2);

  // 2. merged xz (N=512) + xproj (N=64) GEMM -- ONE dispatch
  gemm_xzxp<<<dim3(BL/64, 9), 256, 0, stream>>>(
      h0b, h1b, wbuf1, wb_xp, xz_b, xd);

  // 3. front: conv+silu+delta + local scan w/ C-apply -> pack(y0,de), S, Hout
  //    (d-split geometry: 2 blocks of 128 threads per (chunk,b,dir))
  front_kernel<<<dim3(CH, BB*2, 2), 128, 0, stream>>>(
      xz_b, xd, conv_w_f, conv_b_f, conv_w_bw, conv_b_bw,
      dtproj_w_f, dtproj_b_f, dtproj_w_bw, dtproj_b_bw,
      A_log_f, A_log_bw, D_f, D_bw, xde, Sp, Hout);

  // 4. chunk-carry scan (2-level, in-place Hout->Hin)
  scan_p2<<<dim3(2*BB*DD), 64, 0, stream>>>(Sp, Hout, A_log_f, A_log_bw);

  // 5. fused correction + combine + rmsnorm + gate -> ycomb_b (r0)
  back_kernel<<<dim3(CH, BB), 256, 0, stream>>>(
      xde, xd, A_log_f, A_log_bw, Hin, xz_b, norm_y_w, ycomb_b);

  // 6. x = y @ out_proj.T + residual(x0) -> d_out (fp32)
  gemm_mfma<2><<<dim3(BL/64, 4), 256, 0, stream>>>(
      ycomb_b, wb_out, out, x0, nullptr, BL, 256, 256);

  // 7. m1 = x @ fc1.T (A staged from fp32 out; overwrites dead xde)
  gemm_fc1<<<dim3(BL/64, 2), 256, 0, stream>>>(out, wb_fc1, m1);

  // 8. out += silu(dwconv3(m1)) @ fc2.T  (dwconv fused into A-staging)
  gemm_fc2dw<<<dim3(BL/64, 4), 256, 0, stream>>>(m1, wb_fc2, dw_w, dw_b, out);
}

// Round 10
// 251.132 us; speedup vs baseline: 2.6683x; 1.0030x over previous
//
#include <hip/hip_runtime.h>
#include <math.h>
#include <cstddef>

#define BB 4
#define LL 4096
#define DD 256
#define NST 8
#define RANK 16
#define HID 128
#define BL (BB*LL)          // 16384
#define BLD ((size_t)BL*DD) // 4194304
#define CH 256              // scan chunks
#define CLEN 16             // steps per chunk (CH*CLEN == LL)
#define XZS 512             // xz row stride (xin cols 0..255, z cols 256..511)

typedef __bf16 bf16x8 __attribute__((ext_vector_type(8)));
typedef float  f32x4  __attribute__((ext_vector_type(4)));

__device__ __forceinline__ float siluf(float x){ return x / (1.f + __expf(-x)); }
__device__ __forceinline__ float softplus_fast(float x){
  float r = __logf(1.f + __expf(x));
  return x > 15.f ? x : r;
}
// fp32 -> bf16 bits, round-to-nearest-even
__device__ __forceinline__ unsigned short f2bf(float x){
  union { float f; unsigned u; } v; v.f = x;
  unsigned r = v.u + 0x7fffu + ((v.u >> 16) & 1u);
  return (unsigned short)(r >> 16);
}
__device__ __forceinline__ float bf2f(unsigned short u){
  union { unsigned u32; float f; } c; c.u32 = ((unsigned)u) << 16;
  return c.f;
}

// --- async global->LDS, 16B/lane (1KB/wave-instr), linear LDS dest -------------
#define GLD16(gp, lp) __builtin_amdgcn_global_load_lds( \
    (const __attribute__((address_space(1))) unsigned int*)(gp), \
    (__attribute__((address_space(3))) unsigned int*)(lp), 16, 0, 0)

// swizzled-granule read: logical (row, g) -> granule row*GPR + (g ^ (row&7)).
// 16B granules; reads are <=2 lanes/bank (free, m136).
#define LDSGK(base, row, g, GPR) \
  (*(const bf16x8*)((base) + ((((row)*(GPR)) + ((g) ^ ((row)&7))) << 3)))
// swizzled ushort4 write (col%8 in {0,4}) matching LDSGK layout
#define LDSW4(base, row, col, GPR, u) \
  *(ushort4*)((base) + ((((row)*(GPR)) + ((((col)>>3)) ^ ((row)&7))) << 3) + ((col)&7)) = (u)

// =============== Pre: RMSNorm (both streams) + weight cvt, ONE dispatch ==========
__global__ __launch_bounds__(256) void pre_kernel(
    const float* __restrict__ x0, const float* __restrict__ w0, unsigned short* __restrict__ o0b,
    const float* __restrict__ x1, const float* __restrict__ w1, unsigned short* __restrict__ o1b,
    const float* __restrict__ sA,
    const float* __restrict__ s0, const float* __restrict__ s1,
    const float* __restrict__ s2, const float* __restrict__ s3,
    const float* __restrict__ s4,
    unsigned short* __restrict__ d1, unsigned short* __restrict__ d2)
{
  int blk = blockIdx.x;
  if (blk < 8192){
    const float* x; const float* w; unsigned short* o; size_t tok;
    int wv = threadIdx.x >> 6, lane = threadIdx.x & 63;
    if (blk < 4096){ x = x0; w = w0; o = o0b; tok = (size_t)blk*4 + wv; }
    else           { x = x1; w = w1; o = o1b; tok = (size_t)(blk-4096)*4 + wv; }
    float4 v = ((const float4*)(x + tok*DD))[lane];
    float s = v.x*v.x + v.y*v.y + v.z*v.z + v.w*v.w;
    #pragma unroll
    for (int m = 1; m < 64; m <<= 1) s += __shfl_xor(s, m, 64);
    float scale = 1.f / (sqrtf(s) * (1.f/16.f) + 1e-6f);
    float4 wvv = ((const float4*)w)[lane];
    ushort4 r;
    r.x = f2bf(v.x*scale*wvv.x); r.y = f2bf(v.y*scale*wvv.y);
    r.z = f2bf(v.z*scale*wvv.z); r.w = f2bf(v.w*scale*wvv.w);
    ((ushort4*)(o + tok*DD))[lane] = r;
    return;
  }
  int i = (blk - 8192)*256 + threadIdx.x;   // 0..278527
  if (i >= 278528) return;
  if (i < 131072){ d1[i] = f2bf(sA[i]); return; }
  int j = i - 131072;
  float v;
  if (j < 8192)        v = s0[j];
  else if (j < 16384)  v = s1[j - 8192];
  else if (j < 81920)  v = s2[j - 16384];
  else if (j < 114688) v = s3[j - 81920];
  else                 v = s4[j - 114688];
  d2[j] = f2bf(v);
}

// ---------------- bf16 MFMA GEMM, 64x64 tile, FULL-K single-barrier staging ------
// Entire K extent of A and B staged into LDS (32KB+32KB @K=256) via 16
// global_load_lds/wave all in flight, then ONE __syncthreads, then K/32 MFMA
// steps with no further barriers (compiler interleaves ds_read/MFMA via lgkmcnt).
// Removes 3 of 4 barrier drains of the BK=64 loop. EPI: 0=C=acc; 2=C=acc+Add.
template<int EPI, int K>
__global__ __launch_bounds__(256) void gemm_mfma(
    const unsigned short* __restrict__ A, const unsigned short* __restrict__ Bw,
    float* __restrict__ C, const float* __restrict__ Add, int ldc)
{
  constexpr int GPR = K/8;        // granules per row
  constexpr int NI  = GPR/4;      // GLD16 instrs per wave per matrix
  __shared__ __align__(16) unsigned short AsL[64*K];
  __shared__ __align__(16) unsigned short BsL[64*K];
  int tid  = threadIdx.x;
  int row0 = blockIdx.x * 64;
  int col0 = blockIdx.y * 64;
  int wave = tid >> 6, lane = tid & 63;
  int wm = (wave >> 1) * 32, wn = (wave & 1) * 32;
  int lm = lane & 15, kq = lane >> 4;

  #pragma unroll
  for (int i = 0; i < NI; i++){
    int q  = (wave*NI + i)*64 + lane;
    int r  = q / GPR, gq = q % GPR;
    int g  = gq ^ (r & 7);
    GLD16(A  + (size_t)(row0 + r)*K + g*8, AsL + (wave*NI + i)*512);
    GLD16(Bw + (size_t)(col0 + r)*K + g*8, BsL + (wave*NI + i)*512);
  }
  __syncthreads();

  f32x4 acc[2][2];
  #pragma unroll
  for (int i = 0; i < 2; i++)
    #pragma unroll
    for (int j = 0; j < 2; j++) acc[i][j] = (f32x4){0.f,0.f,0.f,0.f};

  #pragma unroll
  for (int ks = 0; ks < K/32; ks++){
    bf16x8 af[2], bfv[2];
    #pragma unroll
    for (int i = 0; i < 2; i++) af[i]  = LDSGK(AsL, wm + i*16 + lm, ks*4 + kq, GPR);
    #pragma unroll
    for (int j = 0; j < 2; j++) bfv[j] = LDSGK(BsL, wn + j*16 + lm, ks*4 + kq, GPR);
    #pragma unroll
    for (int i = 0; i < 2; i++)
      #pragma unroll
      for (int j = 0; j < 2; j++)
        acc[i][j] = __builtin_amdgcn_mfma_f32_16x16x32_bf16(af[i], bfv[j], acc[i][j], 0, 0, 0);
  }

  // C/D layout: col = lane&15, row = (lane>>4)*4 + reg   [m89-verified]
  #pragma unroll
  for (int i = 0; i < 2; i++){
    int rbase = row0 + wm + i*16 + kq*4;
    #pragma unroll
    for (int j = 0; j < 2; j++){
      int col = col0 + wn + j*16 + lm;
      #pragma unroll
      for (int r = 0; r < 4; r++){
        size_t idx = (size_t)(rbase + r)*ldc + col;
        float v = acc[i][j][r];
        if constexpr (EPI == 2) v += Add[idx];
        C[idx] = v;
      }
    }
  }
}

// =============== Merged xz + xproj GEMM, FULL-K single-barrier ===================
// y<8: xz col-tile y (A=h0b, B=in_proj, bf16 out). y==8: xproj (A=h1b, fp32 out).
__global__ __launch_bounds__(256) void gemm_xzxp(
    const unsigned short* __restrict__ A0i, const unsigned short* __restrict__ A1i,
    const unsigned short* __restrict__ B0i, const unsigned short* __restrict__ B1i,
    unsigned short* __restrict__ Cxz, float* __restrict__ Cxd)
{
  constexpr int K = 256, GPR = K/8, NI = GPR/4;
  __shared__ __align__(16) unsigned short AsL[64*K];
  __shared__ __align__(16) unsigned short BsL[64*K];
  int tid  = threadIdx.x;
  bool xp  = (blockIdx.y == 8);
  const unsigned short* A  = xp ? A1i : A0i;
  const unsigned short* Bw = xp ? B1i : B0i;
  int row0 = blockIdx.x * 64;
  int col0 = xp ? 0 : blockIdx.y * 64;
  int wave = tid >> 6, lane = tid & 63;
  int wm = (wave >> 1) * 32, wn = (wave & 1) * 32;
  int lm = lane & 15, kq = lane >> 4;

  #pragma unroll
  for (int i = 0; i < NI; i++){
    int q  = (wave*NI + i)*64 + lane;
    int r  = q / GPR, gq = q % GPR;
    int g  = gq ^ (r & 7);
    GLD16(A  + (size_t)(row0 + r)*K + g*8, AsL + (wave*NI + i)*512);
    GLD16(Bw + (size_t)(col0 + r)*K + g*8, BsL + (wave*NI + i)*512);
  }
  __syncthreads();

  f32x4 acc[2][2];
  #pragma unroll
  for (int i = 0; i < 2; i++)
    #pragma unroll
    for (int j = 0; j < 2; j++) acc[i][j] = (f32x4){0.f,0.f,0.f,0.f};

  #pragma unroll
  for (int ks = 0; ks < K/32; ks++){
    bf16x8 af[2], bfv[2];
    #pragma unroll
    for (int i = 0; i < 2; i++) af[i]  = LDSGK(AsL, wm + i*16 + lm, ks*4 + kq, GPR);
    #pragma unroll
    for (int j = 0; j < 2; j++) bfv[j] = LDSGK(BsL, wn + j*16 + lm, ks*4 + kq, GPR);
    #pragma unroll
    for (int i = 0; i < 2; i++)
      #pragma unroll
      for (int j = 0; j < 2; j++)
        acc[i][j] = __builtin_amdgcn_mfma_f32_16x16x32_bf16(af[i], bfv[j], acc[i][j], 0, 0, 0);
  }

  #pragma unroll
  for (int i = 0; i < 2; i++){
    int rbase = row0 + wm + i*16 + kq*4;
    #pragma unroll
    for (int j = 0; j < 2; j++){
      int col = col0 + wn + j*16 + lm;
      #pragma unroll
      for (int r = 0; r < 4; r++){
        float v = acc[i][j][r];
        if (xp) Cxd[(size_t)(rbase + r)*64  + col] = v;
        else    Cxz[(size_t)(rbase + r)*XZS + col] = f2bf(v);
      }
    }
  }
}

// =============== fc1: fp32-A GEMM, FULL-K (A ds_write swizzled; B gload_lds) =====
__global__ __launch_bounds__(256) void gemm_fc1(
    const float* __restrict__ Afp, const unsigned short* __restrict__ Bw,
    float* __restrict__ C)
{
  constexpr int K = 256, GPR = K/8, NI = GPR/4, LDC = 128;
  __shared__ __align__(16) unsigned short AsL[64*K];
  __shared__ __align__(16) unsigned short BsL[64*K];
  int tid  = threadIdx.x;
  int row0 = blockIdx.x * 64;
  int col0 = blockIdx.y * 64;
  int wave = tid >> 6, lane = tid & 63;
  int wm = (wave >> 1) * 32, wn = (wave & 1) * 32;
  int lm = lane & 15, kq = lane >> 4;
  int sr = tid >> 2, sc16 = (tid & 3) * 16;

  #pragma unroll
  for (int i = 0; i < NI; i++){
    int q  = (wave*NI + i)*64 + lane;
    int r  = q / GPR, gq = q % GPR;
    int g  = gq ^ (r & 7);
    GLD16(Bw + (size_t)(col0 + r)*K + g*8, BsL + (wave*NI + i)*512);
  }
  #pragma unroll
  for (int k0 = 0; k0 < K; k0 += 64){
    const float* ap = &Afp[(size_t)(row0 + sr)*K + k0 + sc16];
    #pragma unroll
    for (int q = 0; q < 4; q++){
      float4 f = *(const float4*)(ap + q*4);
      ushort4 u; u.x = f2bf(f.x); u.y = f2bf(f.y); u.z = f2bf(f.z); u.w = f2bf(f.w);
      LDSW4(AsL, sr, k0 + sc16 + q*4, GPR, u);
    }
  }
  __syncthreads();

  f32x4 acc[2][2];
  #pragma unroll
  for (int i = 0; i < 2; i++)
    #pragma unroll
    for (int j = 0; j < 2; j++) acc[i][j] = (f32x4){0.f,0.f,0.f,0.f};

  #pragma unroll
  for (int ks = 0; ks < K/32; ks++){
    bf16x8 af[2], bfv[2];
    #pragma unroll
    for (int i = 0; i < 2; i++) af[i]  = LDSGK(AsL, wm + i*16 + lm, ks*4 + kq, GPR);
    #pragma unroll
    for (int j = 0; j < 2; j++) bfv[j] = LDSGK(BsL, wn + j*16 + lm, ks*4 + kq, GPR);
    #pragma unroll
    for (int i = 0; i < 2; i++)
      #pragma unroll
      for (int j = 0; j < 2; j++)
        acc[i][j] = __builtin_amdgcn_mfma_f32_16x16x32_bf16(af[i], bfv[j], acc[i][j], 0, 0, 0);
  }

  #pragma unroll
  for (int i = 0; i < 2; i++){
    int rbase = row0 + wm + i*16 + kq*4;
    #pragma unroll
    for (int j = 0; j < 2; j++){
      int col = col0 + wn + j*16 + lm;
      #pragma unroll
      for (int r = 0; r < 4; r++)
        C[(size_t)(rbase + r)*LDC + col] = acc[i][j][r];
    }
  }
}

// =============== fc2 + dwconv/silu fused A-staging, FULL-K (K=128) ===============
__global__ __launch_bounds__(256) void gemm_fc2dw(
    const float* __restrict__ m1, const unsigned short* __restrict__ Bw,
    const float* __restrict__ dww, const float* __restrict__ dwb,
    float* __restrict__ C)
{
  constexpr int K = 128, GPR = K/8, NI = GPR/4, LDC = 256;
  __shared__ __align__(16) unsigned short AsL[64*K];
  __shared__ __align__(16) unsigned short BsL[64*K];
  __shared__ float wS[HID*3];
  __shared__ float bS[HID];
  int tid  = threadIdx.x;
  if (tid < HID){
    bS[tid] = dwb[tid];
    wS[tid*3+0] = dww[tid*3+0];
    wS[tid*3+1] = dww[tid*3+1];
    wS[tid*3+2] = dww[tid*3+2];
  }

  int row0 = blockIdx.x * 64;
  int col0 = blockIdx.y * 64;
  int wave = tid >> 6, lane = tid & 63;
  int wm = (wave >> 1) * 32, wn = (wave & 1) * 32;
  int lm = lane & 15, kq = lane >> 4;
  int r16 = tid >> 4, cc = (tid & 15) * 4;

  #pragma unroll
  for (int i = 0; i < NI; i++){
    int q  = (wave*NI + i)*64 + lane;
    int r  = q / GPR, gq = q % GPR;
    int g  = gq ^ (r & 7);
    GLD16(Bw + (size_t)(col0 + r)*K + g*8, BsL + (wave*NI + i)*512);
  }
  __syncthreads();   // wS/bS ready (GLD16s stay in flight)

  #pragma unroll
  for (int k0 = 0; k0 < K; k0 += 64){
    #pragma unroll
    for (int pp = 0; pp < 4; pp++){
      int r = pp*16 + r16;
      int t = row0 + r;
      int tl = t & (LL-1);
      int c = k0 + cc;
      const float* mrow = &m1[(size_t)t*HID + c];
      float4 vm = *(const float4*)mrow;
      float4 vp = (tl > 0)      ? *(const float4*)(mrow - HID) : (float4){0,0,0,0};
      float4 vn = (tl < LL-1)   ? *(const float4*)(mrow + HID) : (float4){0,0,0,0};
      float a0 = bS[c+0] + wS[(c+0)*3]*vp.x + wS[(c+0)*3+1]*vm.x + wS[(c+0)*3+2]*vn.x;
      float a1 = bS[c+1] + wS[(c+1)*3]*vp.y + wS[(c+1)*3+1]*vm.y + wS[(c+1)*3+2]*vn.y;
      float a2 = bS[c+2] + wS[(c+2)*3]*vp.z + wS[(c+2)*3+1]*vm.z + wS[(c+2)*3+2]*vn.z;
      float a3 = bS[c+3] + wS[(c+3)*3]*vp.w + wS[(c+3)*3+1]*vm.w + wS[(c+3)*3+2]*vn.w;
      ushort4 u;
      u.x = f2bf(siluf(a0)); u.y = f2bf(siluf(a1));
      u.z = f2bf(siluf(a2)); u.w = f2bf(siluf(a3));
      LDSW4(AsL, r, c, GPR, u);
    }
  }
  __syncthreads();

  f32x4 acc[2][2];
  #pragma unroll
  for (int i = 0; i < 2; i++)
    #pragma unroll
    for (int j = 0; j < 2; j++) acc[i][j] = (f32x4){0.f,0.f,0.f,0.f};

  #pragma unroll
  for (int ks = 0; ks < K/32; ks++){
    bf16x8 af[2], bfv[2];
    #pragma unroll
    for (int i = 0; i < 2; i++) af[i]  = LDSGK(AsL, wm + i*16 + lm, ks*4 + kq, GPR);
    #pragma unroll
    for (int j = 0; j < 2; j++) bfv[j] = LDSGK(BsL, wn + j*16 + lm, ks*4 + kq, GPR);
    #pragma unroll
    for (int i = 0; i < 2; i++)
      #pragma unroll
      for (int j = 0; j < 2; j++)
        acc[i][j] = __builtin_amdgcn_mfma_f32_16x16x32_bf16(af[i], bfv[j], acc[i][j], 0, 0, 0);
  }

  #pragma unroll
  for (int i = 0; i < 2; i++){
    int rbase = row0 + wm + i*16 + kq*4;
    #pragma unroll
    for (int j = 0; j < 2; j++){
      int col = col0 + wn + j*16 + lm;
      #pragma unroll
      for (int r = 0; r < 4; r++){
        size_t idx = (size_t)(rbase + r)*LDC + col;
        C[idx] = C[idx] + acc[i][j][r];
      }
    }
  }
}

// =================== Front: conv+silu+delta + local scan w/ C-apply ==============
// MEASURED-BEST (43.2us, VGPR 80, occ 24%; r7 exact). Known-bad: merged loop
// (67us), e-tree (54us), d-split geometry (45.4us, r9). ACCEPTED -- do not touch.
__global__ __launch_bounds__(256) void front_kernel(
    const unsigned short* __restrict__ xz,
    const float* __restrict__ xd,
    const float* __restrict__ cwf, const float* __restrict__ cbf,
    const float* __restrict__ cwb, const float* __restrict__ cbb,
    const float* __restrict__ dtwf, const float* __restrict__ dtbf,
    const float* __restrict__ dtwb, const float* __restrict__ dtbb,
    const float* __restrict__ Alogf, const float* __restrict__ Alogb,
    const float* __restrict__ Dfp, const float* __restrict__ Dbp,
    unsigned int* __restrict__ xde,
    float* __restrict__ Sp, float* __restrict__ Hout)
{
  int chunk = blockIdx.x, b = blockIdx.y, dir = blockIdx.z;
  int s0 = chunk*CLEN;
  int d  = threadIdx.x;

  __shared__ float sdt[CLEN][16];   // 1 KB
  __shared__ float sB [CLEN][8];    // 0.5 KB
  __shared__ float sC [CLEN][8];    // 0.5 KB
  #pragma unroll
  for (int e = threadIdx.x; e < CLEN*32; e += 256){
    int lt = e >> 5, col = e & 31;
    int pos = s0 + lt;
    int row = dir ? (LL-1-pos) : pos;
    float v = xd[((size_t)b*LL + row)*64 + dir*32 + col];
    if (col < 16)      sdt[lt][col]    = v;
    else if (col < 24) sB [lt][col-16] = v;
    else               sC [lt][col-24] = v;
  }
  __syncthreads();

  float4 cw = ((const float4*)(dir ? cwb : cwf))[d];
  float cb  = (dir ? cbb : cbf)[d];
  const float* dtw = (dir ? dtwb : dtwf) + d*RANK;
  float4 w0 = ((const float4*)dtw)[0], w1 = ((const float4*)dtw)[1];
  float4 w2 = ((const float4*)dtw)[2], w3 = ((const float4*)dtw)[3];
  float dtb = (dir ? dtbb : dtbf)[d];
  float Dd  = (dir ? Dbp : Dfp)[d];

  const unsigned short* xp = xz + (size_t)b*LL*XZS + d;
  #define LDX(pos) ((pos) >= 0 ? bf2f(xp[(size_t)(dir ? (LL-1-(pos)) : (pos))*XZS]) : 0.f)

  // ---- phase 1: conv + silu + delta, packed into regs (full ILP) ----
  float xv[CLEN+3];
  xv[0] = LDX(s0-3); xv[1] = LDX(s0-2); xv[2] = LDX(s0-1);
  #pragma unroll
  for (int i = 0; i < CLEN; i++) xv[3+i] = LDX(s0+i);
  #undef LDX

  unsigned packX[CLEN];
  #pragma unroll
  for (int i = 0; i < CLEN; i++){
    float xc = cb;
    xc = fmaf(cw.x, xv[i],   xc); xc = fmaf(cw.y, xv[i+1], xc);
    xc = fmaf(cw.z, xv[i+2], xc); xc = fmaf(cw.w, xv[i+3], xc);
    xc = siluf(xc);
    const float* dt = &sdt[i][0];
    float de = dtb;
    de = fmaf(dt[0],w0.x, fmaf(dt[1],w0.y, fmaf(dt[2],w0.z, fmaf(dt[3],w0.w, de))));
    de = fmaf(dt[4],w1.x, fmaf(dt[5],w1.y, fmaf(dt[6],w1.z, fmaf(dt[7],w1.w, de))));
    de = fmaf(dt[8],w2.x, fmaf(dt[9],w2.y, fmaf(dt[10],w2.z, fmaf(dt[11],w2.w, de))));
    de = fmaf(dt[12],w3.x, fmaf(dt[13],w3.y, fmaf(dt[14],w3.z, fmaf(dt[15],w3.w, de))));
    de = softplus_fast(de);
    packX[i] = (unsigned)f2bf(xc) | ((unsigned)f2bf(de) << 16);
  }

  // ---- phase 2: local scan (h from 0) with C-apply; write pack (y0,de) ----
  const float* Alog = dir ? Alogb : Alogf;
  float A[NST];
  bool fast = true;
  #pragma unroll
  for (int n = 0; n < NST; n++){
    A[n] = -__expf(Alog[d*NST + n]);
    fast = fast && (fabsf(A[n] + (float)(n+1)) < 1e-3f);
  }
  float h[NST];
  #pragma unroll
  for (int n = 0; n < NST; n++) h[n] = 0.f;
  float S = 0.f;

  unsigned int* xout = xde + ((size_t)(dir*BB + b)*LL + s0)*DD + d;

  if (fast){
    #pragma unroll
    for (int t = 0; t < CLEN; t++){
      unsigned pk = packX[t];
      float xc = bf2f((unsigned short)(pk & 0xffffu));
      float de = bf2f((unsigned short)(pk >> 16));
      S += de;
      float dux = de * xc;
      const float* Bv = &sB[t][0];
      const float* Cv = &sC[t][0];
      float e1 = __expf(-de);
      float dA = e1;
      float acc = xc * Dd;
      h[0] = fmaf(dA, h[0], dux*Bv[0]); acc = fmaf(h[0], Cv[0], acc); dA *= e1;
      h[1] = fmaf(dA, h[1], dux*Bv[1]); acc = fmaf(h[1], Cv[1], acc); dA *= e1;
      h[2] = fmaf(dA, h[2], dux*Bv[2]); acc = fmaf(h[2], Cv[2], acc); dA *= e1;
      h[3] = fmaf(dA, h[3], dux*Bv[3]); acc = fmaf(h[3], Cv[3], acc); dA *= e1;
      h[4] = fmaf(dA, h[4], dux*Bv[4]); acc = fmaf(h[4], Cv[4], acc); dA *= e1;
      h[5] = fmaf(dA, h[5], dux*Bv[5]); acc = fmaf(h[5], Cv[5], acc); dA *= e1;
      h[6] = fmaf(dA, h[6], dux*Bv[6]); acc = fmaf(h[6], Cv[6], acc); dA *= e1;
      h[7] = fmaf(dA, h[7], dux*Bv[7]); acc = fmaf(h[7], Cv[7], acc);
      xout[(size_t)t*DD] = (pk & 0xffff0000u) | (unsigned)f2bf(acc);
    }
  } else {
    #pragma unroll
    for (int t = 0; t < CLEN; t++){
      unsigned pk = packX[t];
      float xc = bf2f((unsigned short)(pk & 0xffffu));
      float de = bf2f((unsigned short)(pk >> 16));
      S += de;
      float dux = de * xc;
      const float* Bv = &sB[t][0];
      const float* Cv = &sC[t][0];
      float acc = xc * Dd;
      #pragma unroll
      for (int n = 0; n < NST; n++){
        h[n] = fmaf(__expf(de*A[n]), h[n], dux*Bv[n]);
        acc = fmaf(h[n], Cv[n], acc);
      }
      xout[(size_t)t*DD] = (pk & 0xffff0000u) | (unsigned)f2bf(acc);
    }
  }

  size_t ob = ((((size_t)dir*CH + chunk)*BB + b)*DD + d)*NST;
  float4 h0v, h1v;
  h0v.x=h[0]; h0v.y=h[1]; h0v.z=h[2]; h0v.w=h[3];
  h1v.x=h[4]; h1v.y=h[5]; h1v.z=h[6]; h1v.w=h[7];
  *(float4*)&Hout[ob]   = h0v; *(float4*)&Hout[ob+4] = h1v;
  Sp[((size_t)(dir*CH + chunk)*BB + b)*DD + d] = S;
}

// Phase 2: chunk-carry scan, 2-level. Block = (dir,b,d) -> 2048 one-wave blocks.
__global__ __launch_bounds__(64) void scan_p2(
    const float* __restrict__ Sp, float* H,
    const float* __restrict__ Alogf, const float* __restrict__ Alogb)
{
  const int SEGC = CH/8;    // 32 chunks per segment
  int blk = blockIdx.x;
  int d   = blk & (DD-1);
  int b   = (blk >> 8) & (BB-1);
  int dir = blk >> 10;
  int t   = threadIdx.x;
  int seg = t >> 3, n = t & 7;
  float A = -__expf((dir ? Alogb : Alogf)[d*NST + n]);

  const size_t sstr = (size_t)BB*DD;          // per-chunk stride in Sp
  const size_t hstr = (size_t)BB*DD*NST;      // per-chunk stride in H
  size_t sb = (size_t)dir*CH*sstr + (size_t)b*DD + d;
  size_t hb = (size_t)dir*CH*hstr + ((size_t)b*DD + d)*NST + n;
  int c0 = seg*SEGC;

  float pv[SEGC], hv[SEGC];
  #pragma unroll
  for (int k = 0; k < SEGC; k++){
    pv[k] = Sp[sb + (size_t)(c0+k)*sstr];
    hv[k] = H [hb + (size_t)(c0+k)*hstr];
  }
  float h = 0.f, Ss = 0.f;
  #pragma unroll
  for (int k = 0; k < SEGC; k++){
    Ss += pv[k];
    pv[k] = __expf(pv[k]*A);
    h = fmaf(pv[k], h, hv[k]);
  }
  float pi = __expf(Ss*A), hi = h;
  #pragma unroll
  for (int off = 8; off < 64; off <<= 1){
    float hprev = __shfl_up(hi, off, 64);
    float pprev = __shfl_up(pi, off, 64);
    if (t >= off){ hi = fmaf(pi, hprev, hi); pi *= pprev; }
  }
  float hin = __shfl_up(hi, 8, 64);
  h = (seg == 0) ? 0.f : hin;
  #pragma unroll
  for (int k = 0; k < SEGC; k++){
    size_t idx = hb + (size_t)(c0+k)*hstr;
    H[idx] = h;
    h = fmaf(pv[k], h, hv[k]);
  }
}

// =================== Back: correction + combine + rmsnorm + gate ==================
// Serial q*=E chain (measured-best; the E-tree variant regressed via VGPR).
__global__ __launch_bounds__(256) void back_kernel(
    const unsigned int* __restrict__ xde,
    const float* __restrict__ xd,
    const float* __restrict__ Alogf, const float* __restrict__ Alogb,
    const float* __restrict__ Hin,
    const unsigned short* __restrict__ xz,
    const float* __restrict__ wn,
    unsigned short* __restrict__ outb)
{
  int c  = blockIdx.x, b = blockIdx.y;
  int cbk = CH-1-c;
  int d  = threadIdx.x;
  int T0 = c*CLEN;          // token base (fwd storage base)
  int Pb = cbk*CLEN;        // bwd storage base; storage Pb+k <-> token T0+15-k

  __shared__ float sCf[CLEN][8], sCb[CLEN][8];  // 1 KB
  __shared__ float red[CLEN][4];
  __shared__ float sscale[CLEN];
  {
    int k  = threadIdx.x & 7;
    int lt = (threadIdx.x >> 3) & 15;
    if (threadIdx.x < 128)
      sCf[lt][k] = xd[((size_t)b*LL + T0 + lt)*64 + 24 + k];
    else
      sCb[lt][k] = xd[((size_t)b*LL + (T0 + 15 - lt))*64 + 56 + k];
  }
  __syncthreads();

  float Af[NST], Ab[NST];
  bool fast = true;
  #pragma unroll
  for (int n = 0; n < NST; n++){
    Af[n] = -__expf(Alogf[d*NST + n]);
    Ab[n] = -__expf(Alogb[d*NST + n]);
    fast = fast && (fabsf(Af[n] + (float)(n+1)) < 1e-3f)
                && (fabsf(Ab[n] + (float)(n+1)) < 1e-3f);
  }

  float vf[CLEN];

  // ---- forward correction ----
  {
    float hn[NST];
    size_t ib = (((size_t)c*BB + b)*DD + d)*NST;                 // dir=0
    float4 a0 = *(const float4*)&Hin[ib];
    float4 a1 = *(const float4*)&Hin[ib+4];
    hn[0]=a0.x; hn[1]=a0.y; hn[2]=a0.z; hn[3]=a0.w;
    hn[4]=a1.x; hn[5]=a1.y; hn[6]=a1.z; hn[7]=a1.w;
    const unsigned int* p = xde + ((size_t)b*LL + T0)*DD + d;    // dir=0 plane
    unsigned int pk[CLEN];
    #pragma unroll
    for (int t = 0; t < CLEN; t++) pk[t] = p[(size_t)t*DD];
    float S = 0.f;
    if (fast){
      #pragma unroll
      for (int t = 0; t < CLEN; t++){
        float y0 = bf2f((unsigned short)(pk[t] & 0xffffu));
        float de = bf2f((unsigned short)(pk[t] >> 16));
        S += de;
        float E = __expf(-S);
        float q = E;
        float corr = q * (hn[0]*sCf[t][0]);
        q *= E; corr = fmaf(q, hn[1]*sCf[t][1], corr);
        q *= E; corr = fmaf(q, hn[2]*sCf[t][2], corr);
        q *= E; corr = fmaf(q, hn[3]*sCf[t][3], corr);
        q *= E; corr = fmaf(q, hn[4]*sCf[t][4], corr);
        q *= E; corr = fmaf(q, hn[5]*sCf[t][5], corr);
        q *= E; corr = fmaf(q, hn[6]*sCf[t][6], corr);
        q *= E; corr = fmaf(q, hn[7]*sCf[t][7], corr);
        vf[t] = y0 + corr;
      }
    } else {
      #pragma unroll
      for (int t = 0; t < CLEN; t++){
        float y0 = bf2f((unsigned short)(pk[t] & 0xffffu));
        float de = bf2f((unsigned short)(pk[t] >> 16));
        S += de;
        float corr = 0.f;
        #pragma unroll
        for (int n = 0; n < NST; n++)
          corr = fmaf(__expf(S*Af[n]), hn[n]*sCf[t][n], corr);
        vf[t] = y0 + corr;
      }
    }
  }

  // ---- backward correction, merged into vf (token j pairs with bwd k=15-j) ----
  {
    float hn[NST];
    size_t ib = ((((size_t)CH + cbk)*BB + b)*DD + d)*NST;        // dir=1
    float4 a0 = *(const float4*)&Hin[ib];
    float4 a1 = *(const float4*)&Hin[ib+4];
    hn[0]=a0.x; hn[1]=a0.y; hn[2]=a0.z; hn[3]=a0.w;
    hn[4]=a1.x; hn[5]=a1.y; hn[6]=a1.z; hn[7]=a1.w;
    const unsigned int* p = xde + ((size_t)(BB + b)*LL + Pb)*DD + d;  // dir=1 plane
    unsigned int pk[CLEN];
    #pragma unroll
    for (int t = 0; t < CLEN; t++) pk[t] = p[(size_t)t*DD];
    float S = 0.f;
    if (fast){
      #pragma unroll
      for (int t = 0; t < CLEN; t++){
        float y0 = bf2f((unsigned short)(pk[t] & 0xffffu));
        float de = bf2f((unsigned short)(pk[t] >> 16));
        S += de;
        float E = __expf(-S);
        float q = E;
        float corr = q * (hn[0]*sCb[t][0]);
        q *= E; corr = fmaf(q, hn[1]*sCb[t][1], corr);
        q *= E; corr = fmaf(q, hn[2]*sCb[t][2], corr);
        q *= E; corr = fmaf(q, hn[3]*sCb[t][3], corr);
        q *= E; corr = fmaf(q, hn[4]*sCb[t][4], corr);
        q *= E; corr = fmaf(q, hn[5]*sCb[t][5], corr);
        q *= E; corr = fmaf(q, hn[6]*sCb[t][6], corr);
        q *= E; corr = fmaf(q, hn[7]*sCb[t][7], corr);
        int j = 15 - t;
        vf[j] = 0.5f*(vf[j] + y0 + corr);
      }
    } else {
      #pragma unroll
      for (int t = 0; t < CLEN; t++){
        float y0 = bf2f((unsigned short)(pk[t] & 0xffffu));
        float de = bf2f((unsigned short)(pk[t] >> 16));
        S += de;
        float corr = 0.f;
        #pragma unroll
        for (int n = 0; n < NST; n++)
          corr = fmaf(__expf(S*Ab[n]), hn[n]*sCb[t][n], corr);
        int j = 15 - t;
        vf[j] = 0.5f*(vf[j] + y0 + corr);
      }
    }
  }

  // ---- per-token RMS reduce over d ----
  int wave = d >> 6, lane = d & 63;
  #pragma unroll
  for (int j = 0; j < CLEN; j++){
    float s = vf[j]*vf[j];
    #pragma unroll
    for (int m = 1; m < 64; m <<= 1) s += __shfl_xor(s, m, 64);
    if (lane == 0) red[j][wave] = s;
  }
  __syncthreads();
  if (d < CLEN){
    float s = red[d][0] + red[d][1] + red[d][2] + red[d][3];
    sscale[d] = 1.f / (sqrtf(s)*(1.f/16.f) + 1e-6f);
  }
  __syncthreads();

  float wd = wn[d];
  #pragma unroll
  for (int j = 0; j < CLEN; j++){
    size_t tok = (size_t)b*LL + T0 + j;
    float z = bf2f(xz[tok*XZS + 256 + d]);
    outb[tok*DD + d] = f2bf(vf[j]*sscale[j]*wd*siluf(z));
  }
}

extern "C" void kernel_launch(void* const* d_in, const int* in_sizes, int n_in,
                              void* d_out, int out_size, void* d_ws, size_t ws_size,
                              hipStream_t stream)
{
  const float* x0        = (const float*)d_in[0];
  const float* x1        = (const float*)d_in[1];
  const float* w_norm0   = (const float*)d_in[2];
  const float* w_norm1   = (const float*)d_in[3];
  const float* in_proj_w = (const float*)d_in[4];
  const float* conv_w_f  = (const float*)d_in[5];
  const float* conv_b_f  = (const float*)d_in[6];
  const float* xproj_w_f = (const float*)d_in[7];
  const float* dtproj_w_f= (const float*)d_in[8];
  const float* dtproj_b_f= (const float*)d_in[9];
  const float* A_log_f   = (const float*)d_in[10];
  const float* D_f       = (const float*)d_in[11];
  const float* conv_w_bw = (const float*)d_in[12];
  const float* conv_b_bw = (const float*)d_in[13];
  const float* xproj_w_bw= (const float*)d_in[14];
  const float* dtproj_w_bw=(const float*)d_in[15];
  const float* dtproj_b_bw=(const float*)d_in[16];
  const float* A_log_bw  = (const float*)d_in[17];
  const float* D_bw      = (const float*)d_in[18];
  const float* norm_y_w  = (const float*)d_in[19];
  const float* out_proj_w= (const float*)d_in[20];
  const float* fc1_w     = (const float*)d_in[21];
  const float* dw_w      = (const float*)d_in[22];
  const float* dw_b      = (const float*)d_in[23];
  const float* fc2_w     = (const float*)d_in[24];
  float* out = (float*)d_out;
  float* ws  = (float*)d_ws;

  // region map (floats, BLD each), lifetime-reused
  float* r0 = ws + 0*BLD;   // h0b (bf16) -> ycomb_b (bf16)
  float* r1 = ws + 1*BLD;   // h1b (bf16)
  float* r2 = ws + 2*BLD;   // xz_b (bf16, BL x 512 = full region)
  float* r3 = ws + 3*BLD;   // xd (fp32 BLx64) -- live through back_kernel
  float* r4 = ws + 4*BLD;   // xde pack (y0,de) (uint32, spans r4+r5) -> m1 (fp32)
  float* r5 = ws + 5*BLD;
  float* r6 = ws + 6*BLD;   // wbuf1 (bf16 in_proj) -> Hout (= Hin, in-place p2)
  float* r7 = ws + 7*BLD;   // wbuf2 (bf16 weights) + S-plane (tail)

  unsigned short* h0b   = (unsigned short*)r0;
  unsigned short* h1b   = (unsigned short*)r1;
  unsigned short* xz_b  = (unsigned short*)r2;   // BL x XZS
  float*          xd    = r3;                    // BL x 64 fp32
  unsigned int*   xde   = (unsigned int*)r4;     // 2*BLD dwords = r4+r5
  unsigned short* wbuf1 = (unsigned short*)r6;   // 131072 (512x256)
  float* Hout = r6;                              // 2*CH*BB*DD*NST = BLD floats
  float* Hin  = Hout;                            // p2 rewrites in place
  const size_t SPLANE = (size_t)2*CH*BB*DD;      // 524288 floats (2 MB)
  float* Sp   = r7 + (BLD - SPLANE);             // tail of r7 (disjoint from wbuf2)
  unsigned short* ycomb_b = (unsigned short*)r0; // r0 free after xz gemm (h0b dead)
  unsigned short* wbuf2   = (unsigned short*)r7;
  unsigned short* wb_xp   = wbuf2;               // 16384  (64x256)
  unsigned short* wb_out  = wbuf2 + 16384;       // 65536
  unsigned short* wb_fc1  = wbuf2 + 81920;       // 32768
  unsigned short* wb_fc2  = wbuf2 + 114688;      // 32768
  float*          m1      = r4;                  // BLx128 fp32 (xde dead by then)

  // 1. pre: rms(x0)->h0b, rms(x1)->h1b, weight conversions -- ONE dispatch
  pre_kernel<<<dim3(9280), 256, 0, stream>>>(
      x0, w_norm0, h0b, x1, w_norm1, h1b,
      in_proj_w, xproj_w_f, xproj_w_bw, out_proj_w, fc1_w, fc2_w, wbuf1, wbuf2);

  // 2. merged xz (N=512) + xproj (N=64) GEMM -- ONE dispatch, full-K staging
  gemm_xzxp<<<dim3(BL/64, 9), 256, 0, stream>>>(
      h0b, h1b, wbuf1, wb_xp, xz_b, xd);

  // 3. front: conv+silu+delta + local scan w/ C-apply -> pack(y0,de), S, Hout
  front_kernel<<<dim3(CH, BB, 2), 256, 0, stream>>>(
      xz_b, xd, conv_w_f, conv_b_f, conv_w_bw, conv_b_bw,
      dtproj_w_f, dtproj_b_f, dtproj_w_bw, dtproj_b_bw,
      A_log_f, A_log_bw, D_f, D_bw, xde, Sp, Hout);

  // 4. chunk-carry scan (2-level, in-place Hout->Hin)
  scan_p2<<<dim3(2*BB*DD), 64, 0, stream>>>(Sp, Hout, A_log_f, A_log_bw);

  // 5. fused correction + combine + rmsnorm + gate -> ycomb_b (r0)
  back_kernel<<<dim3(CH, BB), 256, 0, stream>>>(
      xde, xd, A_log_f, A_log_bw, Hin, xz_b, norm_y_w, ycomb_b);

  // 6. x = y @ out_proj.T + residual(x0) -> d_out (fp32), full-K staging
  gemm_mfma<2, 256><<<dim3(BL/64, 4), 256, 0, stream>>>(
      ycomb_b, wb_out, out, x0, 256);

  // 7. m1 = x @ fc1.T (A staged from fp32 out), full-K
  gemm_fc1<<<dim3(BL/64, 2), 256, 0, stream>>>(out, wb_fc1, m1);

  // 8. out += silu(dwconv3(m1)) @ fc2.T  (dwconv fused into A-staging), full-K
  gemm_fc2dw<<<dim3(BL/64, 4), 256, 0, stream>>>(m1, wb_fc2, dw_w, dw_b, out);
}

// Round 11
// 249.181 us; speedup vs baseline: 2.6892x; 1.0078x over previous
//
#include <hip/hip_runtime.h>
#include <math.h>
#include <cstddef>

#define BB 4
#define LL 4096
#define DD 256
#define NST 8
#define RANK 16
#define HID 128
#define BL (BB*LL)          // 16384
#define BLD ((size_t)BL*DD) // 4194304
#define CH 256              // scan chunks
#define CLEN 16             // steps per chunk (CH*CLEN == LL)
#define XZS 512             // xz row stride (xin cols 0..255, z cols 256..511)

typedef __bf16 bf16x8 __attribute__((ext_vector_type(8)));
typedef float  f32x4  __attribute__((ext_vector_type(4)));

__device__ __forceinline__ float siluf(float x){ return x / (1.f + __expf(-x)); }
__device__ __forceinline__ float softplus_fast(float x){
  float r = __logf(1.f + __expf(x));
  return x > 15.f ? x : r;
}
// fp32 -> bf16 bits, round-to-nearest-even
__device__ __forceinline__ unsigned short f2bf(float x){
  union { float f; unsigned u; } v; v.f = x;
  unsigned r = v.u + 0x7fffu + ((v.u >> 16) & 1u);
  return (unsigned short)(r >> 16);
}
__device__ __forceinline__ float bf2f(unsigned short u){
  union { unsigned u32; float f; } c; c.u32 = ((unsigned)u) << 16;
  return c.f;
}

// --- async global->LDS, 16B/lane (1KB/wave-instr), linear LDS dest -------------
#define GLD16(gp, lp) __builtin_amdgcn_global_load_lds( \
    (const __attribute__((address_space(1))) unsigned int*)(gp), \
    (__attribute__((address_space(3))) unsigned int*)(lp), 16, 0, 0)

// swizzled-granule read: logical (row, g16) -> granule row*8 + (g16 ^ (row&7)).
#define LDSG(base, row, gq) \
  (*(const bf16x8*)((base) + ((((row) << 3) + ((gq) ^ ((row) & 7))) << 3)))

// =============== Pre: RMSNorm (both streams) + weight cvt, ONE dispatch ==========
__global__ __launch_bounds__(256) void pre_kernel(
    const float* __restrict__ x0, const float* __restrict__ w0, unsigned short* __restrict__ o0b,
    const float* __restrict__ x1, const float* __restrict__ w1, unsigned short* __restrict__ o1b,
    const float* __restrict__ sA,
    const float* __restrict__ s0, const float* __restrict__ s1,
    const float* __restrict__ s2, const float* __restrict__ s3,
    const float* __restrict__ s4,
    unsigned short* __restrict__ d1, unsigned short* __restrict__ d2)
{
  int blk = blockIdx.x;
  if (blk < 8192){
    const float* x; const float* w; unsigned short* o; size_t tok;
    int wv = threadIdx.x >> 6, lane = threadIdx.x & 63;
    if (blk < 4096){ x = x0; w = w0; o = o0b; tok = (size_t)blk*4 + wv; }
    else           { x = x1; w = w1; o = o1b; tok = (size_t)(blk-4096)*4 + wv; }
    float4 v = ((const float4*)(x + tok*DD))[lane];
    float s = v.x*v.x + v.y*v.y + v.z*v.z + v.w*v.w;
    #pragma unroll
    for (int m = 1; m < 64; m <<= 1) s += __shfl_xor(s, m, 64);
    float scale = 1.f / (sqrtf(s) * (1.f/16.f) + 1e-6f);
    float4 wvv = ((const float4*)w)[lane];
    ushort4 r;
    r.x = f2bf(v.x*scale*wvv.x); r.y = f2bf(v.y*scale*wvv.y);
    r.z = f2bf(v.z*scale*wvv.z); r.w = f2bf(v.w*scale*wvv.w);
    ((ushort4*)(o + tok*DD))[lane] = r;
    return;
  }
  int i = (blk - 8192)*256 + threadIdx.x;   // 0..278527
  if (i >= 278528) return;
  if (i < 131072){ d1[i] = f2bf(sA[i]); return; }
  int j = i - 131072;
  float v;
  if (j < 8192)        v = s0[j];
  else if (j < 16384)  v = s1[j - 8192];
  else if (j < 81920)  v = s2[j - 16384];
  else if (j < 114688) v = s3[j - 81920];
  else                 v = s4[j - 114688];
  d2[j] = f2bf(v);
}

// ---------------- bf16 MFMA GEMM, 64x64 tile, BK=64, global_load_lds staging -----
// EPI: 0 = C=acc ; 2 = C=acc+Add ; 3 = Cb=bf16(acc)   [r7 measured-best body]
template<int EPI>
__global__ __launch_bounds__(256) void gemm_mfma(
    const unsigned short* __restrict__ A, const unsigned short* __restrict__ Bw,
    float* __restrict__ C, const float* __restrict__ Add,
    unsigned short* __restrict__ Cb, int M, int ldc, int K)
{
  constexpr int BK = 64;
  __shared__ __align__(16) unsigned short AsL[64*64];
  __shared__ __align__(16) unsigned short BsL[64*64];
  int tid  = threadIdx.x;
  int row0 = blockIdx.x * 64;
  int col0 = blockIdx.y * 64;
  int wave = tid >> 6, lane = tid & 63;
  int wm = (wave >> 1) * 32, wn = (wave & 1) * 32;
  int lm = lane & 15, kq = lane >> 4;

  int q0 = wave*128 + lane, q1 = q0 + 64;
  int ra = q0 >> 3, ga = (q0 & 7) ^ (ra & 7);
  int rb = q1 >> 3, gb = (q1 & 7) ^ (rb & 7);
  const unsigned short* A0 = A  + (size_t)(row0 + ra)*K + ga*8;
  const unsigned short* A1 = A  + (size_t)(row0 + rb)*K + gb*8;
  const unsigned short* B0 = Bw + (size_t)(col0 + ra)*K + ga*8;
  const unsigned short* B1 = Bw + (size_t)(col0 + rb)*K + gb*8;
  unsigned short* lA0 = AsL + wave*1024;
  unsigned short* lB0 = BsL + wave*1024;

  f32x4 acc[2][2];
  #pragma unroll
  for (int i = 0; i < 2; i++)
    #pragma unroll
    for (int j = 0; j < 2; j++) acc[i][j] = (f32x4){0.f,0.f,0.f,0.f};

  for (int k0 = 0; k0 < K; k0 += BK){
    GLD16(A0 + k0, lA0);       GLD16(A1 + k0, lA0 + 512);
    GLD16(B0 + k0, lB0);       GLD16(B1 + k0, lB0 + 512);
    __syncthreads();
    #pragma unroll
    for (int ks = 0; ks < 2; ks++){
      bf16x8 af[2], bfv[2];
      #pragma unroll
      for (int i = 0; i < 2; i++) af[i]  = LDSG(AsL, wm + i*16 + lm, ks*4 + kq);
      #pragma unroll
      for (int j = 0; j < 2; j++) bfv[j] = LDSG(BsL, wn + j*16 + lm, ks*4 + kq);
      #pragma unroll
      for (int i = 0; i < 2; i++)
        #pragma unroll
        for (int j = 0; j < 2; j++)
          acc[i][j] = __builtin_amdgcn_mfma_f32_16x16x32_bf16(af[i], bfv[j], acc[i][j], 0, 0, 0);
    }
    __syncthreads();
  }

  #pragma unroll
  for (int i = 0; i < 2; i++){
    int rbase = row0 + wm + i*16 + kq*4;
    #pragma unroll
    for (int j = 0; j < 2; j++){
      int col = col0 + wn + j*16 + lm;
      #pragma unroll
      for (int r = 0; r < 4; r++){
        size_t idx = (size_t)(rbase + r)*ldc + col;
        float v = acc[i][j][r];
        if constexpr (EPI == 2) v += Add[idx];
        if constexpr (EPI != 3) C[idx] = v;
        if constexpr (EPI == 3) Cb[idx] = f2bf(v);
      }
    }
  }
}

// =============== Merged xz + xproj GEMM (gload_lds staging) [r7 body] ============
__global__ __launch_bounds__(256) void gemm_xzxp(
    const unsigned short* __restrict__ A0i, const unsigned short* __restrict__ A1i,
    const unsigned short* __restrict__ B0i, const unsigned short* __restrict__ B1i,
    unsigned short* __restrict__ Cxz, float* __restrict__ Cxd)
{
  constexpr int BK = 64, K = 256;
  __shared__ __align__(16) unsigned short AsL[64*64];
  __shared__ __align__(16) unsigned short BsL[64*64];
  int tid  = threadIdx.x;
  bool xp  = (blockIdx.y == 8);
  const unsigned short* A  = xp ? A1i : A0i;
  const unsigned short* Bw = xp ? B1i : B0i;
  int row0 = blockIdx.x * 64;
  int col0 = xp ? 0 : blockIdx.y * 64;
  int wave = tid >> 6, lane = tid & 63;
  int wm = (wave >> 1) * 32, wn = (wave & 1) * 32;
  int lm = lane & 15, kq = lane >> 4;

  int q0 = wave*128 + lane, q1 = q0 + 64;
  int ra = q0 >> 3, ga = (q0 & 7) ^ (ra & 7);
  int rb = q1 >> 3, gb = (q1 & 7) ^ (rb & 7);
  const unsigned short* A0 = A  + (size_t)(row0 + ra)*K + ga*8;
  const unsigned short* A1 = A  + (size_t)(row0 + rb)*K + gb*8;
  const unsigned short* B0 = Bw + (size_t)(col0 + ra)*K + ga*8;
  const unsigned short* B1 = Bw + (size_t)(col0 + rb)*K + gb*8;
  unsigned short* lA0 = AsL + wave*1024;
  unsigned short* lB0 = BsL + wave*1024;

  f32x4 acc[2][2];
  #pragma unroll
  for (int i = 0; i < 2; i++)
    #pragma unroll
    for (int j = 0; j < 2; j++) acc[i][j] = (f32x4){0.f,0.f,0.f,0.f};

  for (int k0 = 0; k0 < K; k0 += BK){
    GLD16(A0 + k0, lA0);       GLD16(A1 + k0, lA0 + 512);
    GLD16(B0 + k0, lB0);       GLD16(B1 + k0, lB0 + 512);
    __syncthreads();
    #pragma unroll
    for (int ks = 0; ks < 2; ks++){
      bf16x8 af[2], bfv[2];
      #pragma unroll
      for (int i = 0; i < 2; i++) af[i]  = LDSG(AsL, wm + i*16 + lm, ks*4 + kq);
      #pragma unroll
      for (int j = 0; j < 2; j++) bfv[j] = LDSG(BsL, wn + j*16 + lm, ks*4 + kq);
      #pragma unroll
      for (int i = 0; i < 2; i++)
        #pragma unroll
        for (int j = 0; j < 2; j++)
          acc[i][j] = __builtin_amdgcn_mfma_f32_16x16x32_bf16(af[i], bfv[j], acc[i][j], 0, 0, 0);
    }
    __syncthreads();
  }

  #pragma unroll
  for (int i = 0; i < 2; i++){
    int rbase = row0 + wm + i*16 + kq*4;
    #pragma unroll
    for (int j = 0; j < 2; j++){
      int col = col0 + wn + j*16 + lm;
      #pragma unroll
      for (int r = 0; r < 4; r++){
        float v = acc[i][j][r];
        if (xp) Cxd[(size_t)(rbase + r)*64  + col] = v;
        else    Cxz[(size_t)(rbase + r)*XZS + col] = f2bf(v);
      }
    }
  }
}

// =============== fc1: fp32-A GEMM (A padded-LDS convert; B gload_lds) ============
// r7 body except: OUTPUT IS bf16 (m1 feeds only dwconv+silu->bf16; halves the
// store traffic and fc2dw's read footprint).
__global__ __launch_bounds__(256) void gemm_fc1(
    const float* __restrict__ A, const unsigned short* __restrict__ Bw,
    unsigned short* __restrict__ C)
{
  constexpr int BK = 64, PAD = 8, K = 256, LDC = 128;
  __shared__ __align__(16) unsigned short As[64][BK+PAD];
  __shared__ __align__(16) unsigned short BsL[64*64];
  int tid  = threadIdx.x;
  int row0 = blockIdx.x * 64;
  int col0 = blockIdx.y * 64;
  int wave = tid >> 6, lane = tid & 63;
  int wm = (wave >> 1) * 32, wn = (wave & 1) * 32;
  int lm = lane & 15, kq = lane >> 4;
  int sr = tid >> 2, sc16 = (tid & 3) * 16;

  int q0 = wave*128 + lane, q1 = q0 + 64;
  int ra = q0 >> 3, ga = (q0 & 7) ^ (ra & 7);
  int rb = q1 >> 3, gb = (q1 & 7) ^ (rb & 7);
  const unsigned short* B0 = Bw + (size_t)(col0 + ra)*K + ga*8;
  const unsigned short* B1 = Bw + (size_t)(col0 + rb)*K + gb*8;
  unsigned short* lB0 = BsL + wave*1024;

  f32x4 acc[2][2];
  #pragma unroll
  for (int i = 0; i < 2; i++)
    #pragma unroll
    for (int j = 0; j < 2; j++) acc[i][j] = (f32x4){0.f,0.f,0.f,0.f};

  for (int k0 = 0; k0 < K; k0 += BK){
    GLD16(B0 + k0, lB0);       GLD16(B1 + k0, lB0 + 512);
    const float* ap = &A[(size_t)(row0 + sr)*K + k0 + sc16];
    #pragma unroll
    for (int q = 0; q < 4; q++){
      float4 f = *(const float4*)(ap + q*4);
      ushort4 u; u.x = f2bf(f.x); u.y = f2bf(f.y); u.z = f2bf(f.z); u.w = f2bf(f.w);
      *(ushort4*)&As[sr][sc16 + q*4] = u;
    }
    __syncthreads();
    #pragma unroll
    for (int ks = 0; ks < 2; ks++){
      bf16x8 af[2], bfv[2];
      #pragma unroll
      for (int i = 0; i < 2; i++) af[i]  = *(const bf16x8*)&As[wm + i*16 + lm][ks*32 + kq*8];
      #pragma unroll
      for (int j = 0; j < 2; j++) bfv[j] = LDSG(BsL, wn + j*16 + lm, ks*4 + kq);
      #pragma unroll
      for (int i = 0; i < 2; i++)
        #pragma unroll
        for (int j = 0; j < 2; j++)
          acc[i][j] = __builtin_amdgcn_mfma_f32_16x16x32_bf16(af[i], bfv[j], acc[i][j], 0, 0, 0);
    }
    __syncthreads();
  }

  #pragma unroll
  for (int i = 0; i < 2; i++){
    int rbase = row0 + wm + i*16 + kq*4;
    #pragma unroll
    for (int j = 0; j < 2; j++){
      int col = col0 + wn + j*16 + lm;
      #pragma unroll
      for (int r = 0; r < 4; r++)
        C[(size_t)(rbase + r)*LDC + col] = f2bf(acc[i][j][r]);
    }
  }
}

// =============== fc2 with dwconv+silu fused into A-staging (B gload_lds) =========
// r7 body except m1 is bf16 (halved read footprint; halo loads are ushort4).
__global__ __launch_bounds__(256) void gemm_fc2dw(
    const unsigned short* __restrict__ m1, const unsigned short* __restrict__ Bw,
    const float* __restrict__ dww, const float* __restrict__ dwb,
    float* __restrict__ C)
{
  constexpr int BK = 64, PAD = 8, K = 128, LDC = 256;
  __shared__ __align__(16) unsigned short As[64][BK+PAD];
  __shared__ __align__(16) unsigned short BsL[64*64];
  __shared__ float wS[HID*3];
  __shared__ float bS[HID];
  int tid  = threadIdx.x;
  if (tid < HID){
    bS[tid] = dwb[tid];
    wS[tid*3+0] = dww[tid*3+0];
    wS[tid*3+1] = dww[tid*3+1];
    wS[tid*3+2] = dww[tid*3+2];
  }
  __syncthreads();

  int row0 = blockIdx.x * 64;
  int col0 = blockIdx.y * 64;
  int wave = tid >> 6, lane = tid & 63;
  int wm = (wave >> 1) * 32, wn = (wave & 1) * 32;
  int lm = lane & 15, kq = lane >> 4;
  int r16 = tid >> 4, cc = (tid & 15) * 4;

  int q0 = wave*128 + lane, q1 = q0 + 64;
  int ra = q0 >> 3, ga = (q0 & 7) ^ (ra & 7);
  int rb = q1 >> 3, gb = (q1 & 7) ^ (rb & 7);
  const unsigned short* B0 = Bw + (size_t)(col0 + ra)*K + ga*8;
  const unsigned short* B1 = Bw + (size_t)(col0 + rb)*K + gb*8;
  unsigned short* lB0 = BsL + wave*1024;

  f32x4 acc[2][2];
  #pragma unroll
  for (int i = 0; i < 2; i++)
    #pragma unroll
    for (int j = 0; j < 2; j++) acc[i][j] = (f32x4){0.f,0.f,0.f,0.f};

  for (int k0 = 0; k0 < K; k0 += BK){
    GLD16(B0 + k0, lB0);       GLD16(B1 + k0, lB0 + 512);
    // ---- A-stage: dwconv3 + silu from bf16 m1 ----
    #pragma unroll
    for (int pp = 0; pp < 4; pp++){
      int r = pp*16 + r16;
      int t = row0 + r;
      int tl = t & (LL-1);
      int c = k0 + cc;
      const unsigned short* mrow = &m1[(size_t)t*HID + c];
      ushort4 um = *(const ushort4*)mrow;
      ushort4 up = (tl > 0)    ? *(const ushort4*)(mrow - HID) : (ushort4){0,0,0,0};
      ushort4 un = (tl < LL-1) ? *(const ushort4*)(mrow + HID) : (ushort4){0,0,0,0};
      float a0 = bS[c+0] + wS[(c+0)*3]*bf2f(up.x) + wS[(c+0)*3+1]*bf2f(um.x) + wS[(c+0)*3+2]*bf2f(un.x);
      float a1 = bS[c+1] + wS[(c+1)*3]*bf2f(up.y) + wS[(c+1)*3+1]*bf2f(um.y) + wS[(c+1)*3+2]*bf2f(un.y);
      float a2 = bS[c+2] + wS[(c+2)*3]*bf2f(up.z) + wS[(c+2)*3+1]*bf2f(um.z) + wS[(c+2)*3+2]*bf2f(un.z);
      float a3 = bS[c+3] + wS[(c+3)*3]*bf2f(up.w) + wS[(c+3)*3+1]*bf2f(um.w) + wS[(c+3)*3+2]*bf2f(un.w);
      ushort4 u;
      u.x = f2bf(siluf(a0)); u.y = f2bf(siluf(a1));
      u.z = f2bf(siluf(a2)); u.w = f2bf(siluf(a3));
      *(ushort4*)&As[r][cc] = u;
    }
    __syncthreads();
    #pragma unroll
    for (int ks = 0; ks < 2; ks++){
      bf16x8 af[2], bfv[2];
      #pragma unroll
      for (int i = 0; i < 2; i++) af[i]  = *(const bf16x8*)&As[wm + i*16 + lm][ks*32 + kq*8];
      #pragma unroll
      for (int j = 0; j < 2; j++) bfv[j] = LDSG(BsL, wn + j*16 + lm, ks*4 + kq);
      #pragma unroll
      for (int i = 0; i < 2; i++)
        #pragma unroll
        for (int j = 0; j < 2; j++)
          acc[i][j] = __builtin_amdgcn_mfma_f32_16x16x32_bf16(af[i], bfv[j], acc[i][j], 0, 0, 0);
    }
    __syncthreads();
  }

  #pragma unroll
  for (int i = 0; i < 2; i++){
    int rbase = row0 + wm + i*16 + kq*4;
    #pragma unroll
    for (int j = 0; j < 2; j++){
      int col = col0 + wn + j*16 + lm;
      #pragma unroll
      for (int r = 0; r < 4; r++){
        size_t idx = (size_t)(rbase + r)*LDC + col;
        C[idx] = C[idx] + acc[i][j][r];
      }
    }
  }
}

// =================== Front: conv+silu+delta + local scan w/ C-apply ==============
// MEASURED-BEST (43-45us, VGPR 80, occ 24%; r7 exact). Known-bad: merged loop
// (67us), e-tree (54us), d-split (45.4us), persistent fusion (530us). Do not touch.
__global__ __launch_bounds__(256) void front_kernel(
    const unsigned short* __restrict__ xz,
    const float* __restrict__ xd,
    const float* __restrict__ cwf, const float* __restrict__ cbf,
    const float* __restrict__ cwb, const float* __restrict__ cbb,
    const float* __restrict__ dtwf, const float* __restrict__ dtbf,
    const float* __restrict__ dtwb, const float* __restrict__ dtbb,
    const float* __restrict__ Alogf, const float* __restrict__ Alogb,
    const float* __restrict__ Dfp, const float* __restrict__ Dbp,
    unsigned int* __restrict__ xde,
    float* __restrict__ Sp, float* __restrict__ Hout)
{
  int chunk = blockIdx.x, b = blockIdx.y, dir = blockIdx.z;
  int s0 = chunk*CLEN;
  int d  = threadIdx.x;

  __shared__ float sdt[CLEN][16];   // 1 KB
  __shared__ float sB [CLEN][8];    // 0.5 KB
  __shared__ float sC [CLEN][8];    // 0.5 KB
  #pragma unroll
  for (int e = threadIdx.x; e < CLEN*32; e += 256){
    int lt = e >> 5, col = e & 31;
    int pos = s0 + lt;
    int row = dir ? (LL-1-pos) : pos;
    float v = xd[((size_t)b*LL + row)*64 + dir*32 + col];
    if (col < 16)      sdt[lt][col]    = v;
    else if (col < 24) sB [lt][col-16] = v;
    else               sC [lt][col-24] = v;
  }
  __syncthreads();

  float4 cw = ((const float4*)(dir ? cwb : cwf))[d];
  float cb  = (dir ? cbb : cbf)[d];
  const float* dtw = (dir ? dtwb : dtwf) + d*RANK;
  float4 w0 = ((const float4*)dtw)[0], w1 = ((const float4*)dtw)[1];
  float4 w2 = ((const float4*)dtw)[2], w3 = ((const float4*)dtw)[3];
  float dtb = (dir ? dtbb : dtbf)[d];
  float Dd  = (dir ? Dbp : Dfp)[d];

  const unsigned short* xp = xz + (size_t)b*LL*XZS + d;
  #define LDX(pos) ((pos) >= 0 ? bf2f(xp[(size_t)(dir ? (LL-1-(pos)) : (pos))*XZS]) : 0.f)

  // ---- phase 1: conv + silu + delta, packed into regs (full ILP) ----
  float xv[CLEN+3];
  xv[0] = LDX(s0-3); xv[1] = LDX(s0-2); xv[2] = LDX(s0-1);
  #pragma unroll
  for (int i = 0; i < CLEN; i++) xv[3+i] = LDX(s0+i);
  #undef LDX

  unsigned packX[CLEN];
  #pragma unroll
  for (int i = 0; i < CLEN; i++){
    float xc = cb;
    xc = fmaf(cw.x, xv[i],   xc); xc = fmaf(cw.y, xv[i+1], xc);
    xc = fmaf(cw.z, xv[i+2], xc); xc = fmaf(cw.w, xv[i+3], xc);
    xc = siluf(xc);
    const float* dt = &sdt[i][0];
    float de = dtb;
    de = fmaf(dt[0],w0.x, fmaf(dt[1],w0.y, fmaf(dt[2],w0.z, fmaf(dt[3],w0.w, de))));
    de = fmaf(dt[4],w1.x, fmaf(dt[5],w1.y, fmaf(dt[6],w1.z, fmaf(dt[7],w1.w, de))));
    de = fmaf(dt[8],w2.x, fmaf(dt[9],w2.y, fmaf(dt[10],w2.z, fmaf(dt[11],w2.w, de))));
    de = fmaf(dt[12],w3.x, fmaf(dt[13],w3.y, fmaf(dt[14],w3.z, fmaf(dt[15],w3.w, de))));
    de = softplus_fast(de);
    packX[i] = (unsigned)f2bf(xc) | ((unsigned)f2bf(de) << 16);
  }

  // ---- phase 2: local scan (h from 0) with C-apply; write pack (y0,de) ----
  const float* Alog = dir ? Alogb : Alogf;
  float A[NST];
  bool fast = true;
  #pragma unroll
  for (int n = 0; n < NST; n++){
    A[n] = -__expf(Alog[d*NST + n]);
    fast = fast && (fabsf(A[n] + (float)(n+1)) < 1e-3f);
  }
  float h[NST];
  #pragma unroll
  for (int n = 0; n < NST; n++) h[n] = 0.f;
  float S = 0.f;

  unsigned int* xout = xde + ((size_t)(dir*BB + b)*LL + s0)*DD + d;

  if (fast){
    #pragma unroll
    for (int t = 0; t < CLEN; t++){
      unsigned pk = packX[t];
      float xc = bf2f((unsigned short)(pk & 0xffffu));
      float de = bf2f((unsigned short)(pk >> 16));
      S += de;
      float dux = de * xc;
      const float* Bv = &sB[t][0];
      const float* Cv = &sC[t][0];
      float e1 = __expf(-de);
      float dA = e1;
      float acc = xc * Dd;
      h[0] = fmaf(dA, h[0], dux*Bv[0]); acc = fmaf(h[0], Cv[0], acc); dA *= e1;
      h[1] = fmaf(dA, h[1], dux*Bv[1]); acc = fmaf(h[1], Cv[1], acc); dA *= e1;
      h[2] = fmaf(dA, h[2], dux*Bv[2]); acc = fmaf(h[2], Cv[2], acc); dA *= e1;
      h[3] = fmaf(dA, h[3], dux*Bv[3]); acc = fmaf(h[3], Cv[3], acc); dA *= e1;
      h[4] = fmaf(dA, h[4], dux*Bv[4]); acc = fmaf(h[4], Cv[4], acc); dA *= e1;
      h[5] = fmaf(dA, h[5], dux*Bv[5]); acc = fmaf(h[5], Cv[5], acc); dA *= e1;
      h[6] = fmaf(dA, h[6], dux*Bv[6]); acc = fmaf(h[6], Cv[6], acc); dA *= e1;
      h[7] = fmaf(dA, h[7], dux*Bv[7]); acc = fmaf(h[7], Cv[7], acc);
      xout[(size_t)t*DD] = (pk & 0xffff0000u) | (unsigned)f2bf(acc);
    }
  } else {
    #pragma unroll
    for (int t = 0; t < CLEN; t++){
      unsigned pk = packX[t];
      float xc = bf2f((unsigned short)(pk & 0xffffu));
      float de = bf2f((unsigned short)(pk >> 16));
      S += de;
      float dux = de * xc;
      const float* Bv = &sB[t][0];
      const float* Cv = &sC[t][0];
      float acc = xc * Dd;
      #pragma unroll
      for (int n = 0; n < NST; n++){
        h[n] = fmaf(__expf(de*A[n]), h[n], dux*Bv[n]);
        acc = fmaf(h[n], Cv[n], acc);
      }
      xout[(size_t)t*DD] = (pk & 0xffff0000u) | (unsigned)f2bf(acc);
    }
  }

  size_t ob = ((((size_t)dir*CH + chunk)*BB + b)*DD + d)*NST;
  float4 h0v, h1v;
  h0v.x=h[0]; h0v.y=h[1]; h0v.z=h[2]; h0v.w=h[3];
  h1v.x=h[4]; h1v.y=h[5]; h1v.z=h[6]; h1v.w=h[7];
  *(float4*)&Hout[ob]   = h0v; *(float4*)&Hout[ob+4] = h1v;
  Sp[((size_t)(dir*CH + chunk)*BB + b)*DD + d] = S;
}

// Phase 2: chunk-carry scan, 2-level. Block = (dir,b,d) -> 2048 one-wave blocks.
__global__ __launch_bounds__(64) void scan_p2(
    const float* __restrict__ Sp, float* H,
    const float* __restrict__ Alogf, const float* __restrict__ Alogb)
{
  const int SEGC = CH/8;    // 32 chunks per segment
  int blk = blockIdx.x;
  int d   = blk & (DD-1);
  int b   = (blk >> 8) & (BB-1);
  int dir = blk >> 10;
  int t   = threadIdx.x;
  int seg = t >> 3, n = t & 7;
  float A = -__expf((dir ? Alogb : Alogf)[d*NST + n]);

  const size_t sstr = (size_t)BB*DD;          // per-chunk stride in Sp
  const size_t hstr = (size_t)BB*DD*NST;      // per-chunk stride in H
  size_t sb = (size_t)dir*CH*sstr + (size_t)b*DD + d;
  size_t hb = (size_t)dir*CH*hstr + ((size_t)b*DD + d)*NST + n;
  int c0 = seg*SEGC;

  float pv[SEGC], hv[SEGC];
  #pragma unroll
  for (int k = 0; k < SEGC; k++){
    pv[k] = Sp[sb + (size_t)(c0+k)*sstr];
    hv[k] = H [hb + (size_t)(c0+k)*hstr];
  }
  float h = 0.f, Ss = 0.f;
  #pragma unroll
  for (int k = 0; k < SEGC; k++){
    Ss += pv[k];
    pv[k] = __expf(pv[k]*A);
    h = fmaf(pv[k], h, hv[k]);
  }
  float pi = __expf(Ss*A), hi = h;
  #pragma unroll
  for (int off = 8; off < 64; off <<= 1){
    float hprev = __shfl_up(hi, off, 64);
    float pprev = __shfl_up(pi, off, 64);
    if (t >= off){ hi = fmaf(pi, hprev, hi); pi *= pprev; }
  }
  float hin = __shfl_up(hi, 8, 64);
  h = (seg == 0) ? 0.f : hin;
  #pragma unroll
  for (int k = 0; k < SEGC; k++){
    size_t idx = hb + (size_t)(c0+k)*hstr;
    H[idx] = h;
    h = fmaf(pv[k], h, hv[k]);
  }
}

// =================== Back: correction + combine + rmsnorm + gate ==================
// Serial q*=E chain (measured-best; the E-tree variant regressed via VGPR).
__global__ __launch_bounds__(256) void back_kernel(
    const unsigned int* __restrict__ xde,
    const float* __restrict__ xd,
    const float* __restrict__ Alogf, const float* __restrict__ Alogb,
    const float* __restrict__ Hin,
    const unsigned short* __restrict__ xz,
    const float* __restrict__ wn,
    unsigned short* __restrict__ outb)
{
  int c  = blockIdx.x, b = blockIdx.y;
  int cbk = CH-1-c;
  int d  = threadIdx.x;
  int T0 = c*CLEN;          // token base (fwd storage base)
  int Pb = cbk*CLEN;        // bwd storage base; storage Pb+k <-> token T0+15-k

  __shared__ float sCf[CLEN][8], sCb[CLEN][8];  // 1 KB
  __shared__ float red[CLEN][4];
  __shared__ float sscale[CLEN];
  {
    int k  = threadIdx.x & 7;
    int lt = (threadIdx.x >> 3) & 15;
    if (threadIdx.x < 128)
      sCf[lt][k] = xd[((size_t)b*LL + T0 + lt)*64 + 24 + k];
    else
      sCb[lt][k] = xd[((size_t)b*LL + (T0 + 15 - lt))*64 + 56 + k];
  }
  __syncthreads();

  float Af[NST], Ab[NST];
  bool fast = true;
  #pragma unroll
  for (int n = 0; n < NST; n++){
    Af[n] = -__expf(Alogf[d*NST + n]);
    Ab[n] = -__expf(Alogb[d*NST + n]);
    fast = fast && (fabsf(Af[n] + (float)(n+1)) < 1e-3f)
                && (fabsf(Ab[n] + (float)(n+1)) < 1e-3f);
  }

  float vf[CLEN];

  // ---- forward correction ----
  {
    float hn[NST];
    size_t ib = (((size_t)c*BB + b)*DD + d)*NST;                 // dir=0
    float4 a0 = *(const float4*)&Hin[ib];
    float4 a1 = *(const float4*)&Hin[ib+4];
    hn[0]=a0.x; hn[1]=a0.y; hn[2]=a0.z; hn[3]=a0.w;
    hn[4]=a1.x; hn[5]=a1.y; hn[6]=a1.z; hn[7]=a1.w;
    const unsigned int* p = xde + ((size_t)b*LL + T0)*DD + d;    // dir=0 plane
    unsigned int pk[CLEN];
    #pragma unroll
    for (int t = 0; t < CLEN; t++) pk[t] = p[(size_t)t*DD];
    float S = 0.f;
    if (fast){
      #pragma unroll
      for (int t = 0; t < CLEN; t++){
        float y0 = bf2f((unsigned short)(pk[t] & 0xffffu));
        float de = bf2f((unsigned short)(pk[t] >> 16));
        S += de;
        float E = __expf(-S);
        float q = E;
        float corr = q * (hn[0]*sCf[t][0]);
        q *= E; corr = fmaf(q, hn[1]*sCf[t][1], corr);
        q *= E; corr = fmaf(q, hn[2]*sCf[t][2], corr);
        q *= E; corr = fmaf(q, hn[3]*sCf[t][3], corr);
        q *= E; corr = fmaf(q, hn[4]*sCf[t][4], corr);
        q *= E; corr = fmaf(q, hn[5]*sCf[t][5], corr);
        q *= E; corr = fmaf(q, hn[6]*sCf[t][6], corr);
        q *= E; corr = fmaf(q, hn[7]*sCf[t][7], corr);
        vf[t] = y0 + corr;
      }
    } else {
      #pragma unroll
      for (int t = 0; t < CLEN; t++){
        float y0 = bf2f((unsigned short)(pk[t] & 0xffffu));
        float de = bf2f((unsigned short)(pk[t] >> 16));
        S += de;
        float corr = 0.f;
        #pragma unroll
        for (int n = 0; n < NST; n++)
          corr = fmaf(__expf(S*Af[n]), hn[n]*sCf[t][n], corr);
        vf[t] = y0 + corr;
      }
    }
  }

  // ---- backward correction, merged into vf (token j pairs with bwd k=15-j) ----
  {
    float hn[NST];
    size_t ib = ((((size_t)CH + cbk)*BB + b)*DD + d)*NST;        // dir=1
    float4 a0 = *(const float4*)&Hin[ib];
    float4 a1 = *(const float4*)&Hin[ib+4];
    hn[0]=a0.x; hn[1]=a0.y; hn[2]=a0.z; hn[3]=a0.w;
    hn[4]=a1.x; hn[5]=a1.y; hn[6]=a1.z; hn[7]=a1.w;
    const unsigned int* p = xde + ((size_t)(BB + b)*LL + Pb)*DD + d;  // dir=1 plane
    unsigned int pk[CLEN];
    #pragma unroll
    for (int t = 0; t < CLEN; t++) pk[t] = p[(size_t)t*DD];
    float S = 0.f;
    if (fast){
      #pragma unroll
      for (int t = 0; t < CLEN; t++){
        float y0 = bf2f((unsigned short)(pk[t] & 0xffffu));
        float de = bf2f((unsigned short)(pk[t] >> 16));
        S += de;
        float E = __expf(-S);
        float q = E;
        float corr = q * (hn[0]*sCb[t][0]);
        q *= E; corr = fmaf(q, hn[1]*sCb[t][1], corr);
        q *= E; corr = fmaf(q, hn[2]*sCb[t][2], corr);
        q *= E; corr = fmaf(q, hn[3]*sCb[t][3], corr);
        q *= E; corr = fmaf(q, hn[4]*sCb[t][4], corr);
        q *= E; corr = fmaf(q, hn[5]*sCb[t][5], corr);
        q *= E; corr = fmaf(q, hn[6]*sCb[t][6], corr);
        q *= E; corr = fmaf(q, hn[7]*sCb[t][7], corr);
        int j = 15 - t;
        vf[j] = 0.5f*(vf[j] + y0 + corr);
      }
    } else {
      #pragma unroll
      for (int t = 0; t < CLEN; t++){
        float y0 = bf2f((unsigned short)(pk[t] & 0xffffu));
        float de = bf2f((unsigned short)(pk[t] >> 16));
        S += de;
        float corr = 0.f;
        #pragma unroll
        for (int n = 0; n < NST; n++)
          corr = fmaf(__expf(S*Ab[n]), hn[n]*sCb[t][n], corr);
        int j = 15 - t;
        vf[j] = 0.5f*(vf[j] + y0 + corr);
      }
    }
  }

  // ---- per-token RMS reduce over d ----
  int wave = d >> 6, lane = d & 63;
  #pragma unroll
  for (int j = 0; j < CLEN; j++){
    float s = vf[j]*vf[j];
    #pragma unroll
    for (int m = 1; m < 64; m <<= 1) s += __shfl_xor(s, m, 64);
    if (lane == 0) red[j][wave] = s;
  }
  __syncthreads();
  if (d < CLEN){
    float s = red[d][0] + red[d][1] + red[d][2] + red[d][3];
    sscale[d] = 1.f / (sqrtf(s)*(1.f/16.f) + 1e-6f);
  }
  __syncthreads();

  float wd = wn[d];
  #pragma unroll
  for (int j = 0; j < CLEN; j++){
    size_t tok = (size_t)b*LL + T0 + j;
    float z = bf2f(xz[tok*XZS + 256 + d]);
    outb[tok*DD + d] = f2bf(vf[j]*sscale[j]*wd*siluf(z));
  }
}

extern "C" void kernel_launch(void* const* d_in, const int* in_sizes, int n_in,
                              void* d_out, int out_size, void* d_ws, size_t ws_size,
                              hipStream_t stream)
{
  const float* x0        = (const float*)d_in[0];
  const float* x1        = (const float*)d_in[1];
  const float* w_norm0   = (const float*)d_in[2];
  const float* w_norm1   = (const float*)d_in[3];
  const float* in_proj_w = (const float*)d_in[4];
  const float* conv_w_f  = (const float*)d_in[5];
  const float* conv_b_f  = (const float*)d_in[6];
  const float* xproj_w_f = (const float*)d_in[7];
  const float* dtproj_w_f= (const float*)d_in[8];
  const float* dtproj_b_f= (const float*)d_in[9];
  const float* A_log_f   = (const float*)d_in[10];
  const float* D_f       = (const float*)d_in[11];
  const float* conv_w_bw = (const float*)d_in[12];
  const float* conv_b_bw = (const float*)d_in[13];
  const float* xproj_w_bw= (const float*)d_in[14];
  const float* dtproj_w_bw=(const float*)d_in[15];
  const float* dtproj_b_bw=(const float*)d_in[16];
  const float* A_log_bw  = (const float*)d_in[17];
  const float* D_bw      = (const float*)d_in[18];
  const float* norm_y_w  = (const float*)d_in[19];
  const float* out_proj_w= (const float*)d_in[20];
  const float* fc1_w     = (const float*)d_in[21];
  const float* dw_w      = (const float*)d_in[22];
  const float* dw_b      = (const float*)d_in[23];
  const float* fc2_w     = (const float*)d_in[24];
  float* out = (float*)d_out;
  float* ws  = (float*)d_ws;

  // region map (floats, BLD each), lifetime-reused
  float* r0 = ws + 0*BLD;   // h0b (bf16) -> ycomb_b (bf16)
  float* r1 = ws + 1*BLD;   // h1b (bf16)
  float* r2 = ws + 2*BLD;   // xz_b (bf16, BL x 512 = full region)
  float* r3 = ws + 3*BLD;   // xd (fp32 BLx64) -- live through back_kernel
  float* r4 = ws + 4*BLD;   // xde pack (y0,de) (uint32, spans r4+r5) -> m1b (bf16)
  float* r5 = ws + 5*BLD;
  float* r6 = ws + 6*BLD;   // wbuf1 (bf16 in_proj) -> Hout (= Hin, in-place p2)
  float* r7 = ws + 7*BLD;   // wbuf2 (bf16 weights) + S-plane (tail)

  unsigned short* h0b   = (unsigned short*)r0;
  unsigned short* h1b   = (unsigned short*)r1;
  unsigned short* xz_b  = (unsigned short*)r2;   // BL x XZS
  float*          xd    = r3;                    // BL x 64 fp32
  unsigned int*   xde   = (unsigned int*)r4;     // 2*BLD dwords = r4+r5
  unsigned short* wbuf1 = (unsigned short*)r6;   // 131072 (512x256)
  float* Hout = r6;                              // 2*CH*BB*DD*NST = BLD floats
  float* Hin  = Hout;                            // p2 rewrites in place
  const size_t SPLANE = (size_t)2*CH*BB*DD;      // 524288 floats (2 MB)
  float* Sp   = r7 + (BLD - SPLANE);             // tail of r7 (disjoint from wbuf2)
  unsigned short* ycomb_b = (unsigned short*)r0; // r0 free after xz gemm (h0b dead)
  unsigned short* wbuf2   = (unsigned short*)r7;
  unsigned short* wb_xp   = wbuf2;               // 16384  (64x256)
  unsigned short* wb_out  = wbuf2 + 16384;       // 65536
  unsigned short* wb_fc1  = wbuf2 + 81920;       // 32768
  unsigned short* wb_fc2  = wbuf2 + 114688;      // 32768
  unsigned short* m1b     = (unsigned short*)r4; // BLx128 bf16 (xde dead by then)

  // 1. pre: rms(x0)->h0b, rms(x1)->h1b, weight conversions -- ONE dispatch
  pre_kernel<<<dim3(9280), 256, 0, stream>>>(
      x0, w_norm0, h0b, x1, w_norm1, h1b,
      in_proj_w, xproj_w_f, xproj_w_bw, out_proj_w, fc1_w, fc2_w, wbuf1, wbuf2);

  // 2. merged xz (N=512) + xproj (N=64) GEMM -- ONE dispatch
  gemm_xzxp<<<dim3(BL/64, 9), 256, 0, stream>>>(
      h0b, h1b, wbuf1, wb_xp, xz_b, xd);

  // 3. front: conv+silu+delta + local scan w/ C-apply -> pack(y0,de), S, Hout
  front_kernel<<<dim3(CH, BB, 2), 256, 0, stream>>>(
      xz_b, xd, conv_w_f, conv_b_f, conv_w_bw, conv_b_bw,
      dtproj_w_f, dtproj_b_f, dtproj_w_bw, dtproj_b_bw,
      A_log_f, A_log_bw, D_f, D_bw, xde, Sp, Hout);

  // 4. chunk-carry scan (2-level, in-place Hout->Hin)
  scan_p2<<<dim3(2*BB*DD), 64, 0, stream>>>(Sp, Hout, A_log_f, A_log_bw);

  // 5. fused correction + combine + rmsnorm + gate -> ycomb_b (r0)
  back_kernel<<<dim3(CH, BB), 256, 0, stream>>>(
      xde, xd, A_log_f, A_log_bw, Hin, xz_b, norm_y_w, ycomb_b);

  // 6. x = y @ out_proj.T + residual(x0) -> d_out (fp32)
  gemm_mfma<2><<<dim3(BL/64, 4), 256, 0, stream>>>(
      ycomb_b, wb_out, out, x0, nullptr, BL, 256, 256);

  // 7. m1 = x @ fc1.T -> bf16 (halved store; overwrites dead xde)
  gemm_fc1<<<dim3(BL/64, 2), 256, 0, stream>>>(out, wb_fc1, m1b);

  // 8. out += silu(dwconv3(m1)) @ fc2.T  (dwconv fused into A-staging, bf16 m1)
  gemm_fc2dw<<<dim3(BL/64, 4), 256, 0, stream>>>(m1b, wb_fc2, dw_w, dw_b, out);
}